// Round 1
// baseline (3859.173 us; speedup 1.0000x reference)
//
#include <hip/hip_runtime.h>
#include <cstdint>
#include <cstddef>

typedef __bf16 bf16;
typedef __bf16 bf16x8 __attribute__((ext_vector_type(8)));
typedef float f32x4 __attribute__((ext_vector_type(4)));

#define L_SEQ   1024
#define DMODEL  512
#define DINNER  1024
#define DSTATE  16
#define NHEADS  16
#define HEADDIM 64
#define CONVDIM 1056
#define DINPROJ 2096
#define FFN_DIM 2048
#define ROWS    2048   // B*L

__device__ __forceinline__ float wave_sum(float v) {
#pragma unroll
  for (int off = 32; off; off >>= 1) v += __shfl_down(v, off, 64);
  return v;
}

__device__ __forceinline__ float silu_f(float x) { return x / (1.0f + expf(-x)); }

// ---------------- RMS norm (+ optional pe/mask), C = 512 ----------------
__global__ __launch_bounds__(128) void rms_kernel(
    const float* __restrict__ x, const float* __restrict__ w,
    const float* __restrict__ pe, const float* __restrict__ mask,
    float* __restrict__ out, float eps)
{
  int r = blockIdx.x;
  int t = threadIdx.x;
  float4 v = ((const float4*)(x + (size_t)r * DMODEL))[t];
  float ss = v.x*v.x + v.y*v.y + v.z*v.z + v.w*v.w;
  ss = wave_sum(ss);
  __shared__ float red[2];
  if ((t & 63) == 0) red[t >> 6] = ss;
  __syncthreads();
  float total = red[0] + red[1];
  float rs = 1.0f / sqrtf(total * (1.0f / DMODEL) + eps);
  float4 wv = ((const float4*)w)[t];
  float4 o;
  o.x = v.x*rs*wv.x; o.y = v.y*rs*wv.y; o.z = v.z*rs*wv.z; o.w = v.w*rs*wv.w;
  if (pe) {
    float4 p = ((const float4*)(pe + (size_t)r * DMODEL))[t];
    float m = mask[r];
    o.x = (o.x + p.x)*m; o.y = (o.y + p.y)*m; o.z = (o.z + p.z)*m; o.w = (o.w + p.w)*m;
  }
  ((float4*)(out + (size_t)r * DMODEL))[t] = o;
}

// ---------------- transpose + f32->bf16: WT[n][k] = W[k][n] ----------------
__global__ __launch_bounds__(256) void transpose_cvt(
    const float* __restrict__ W, bf16* __restrict__ WT, int K, int N)
{
  __shared__ float tile[32][33];
  int z = blockIdx.z;
  const float* Wz = W + (size_t)z * K * N;
  bf16* WTz = WT + (size_t)z * N * K;
  int k0 = blockIdx.x * 32, n0 = blockIdx.y * 32;
  int tx = threadIdx.x & 31, ty = threadIdx.x >> 5;
#pragma unroll
  for (int i = 0; i < 4; i++) {
    int k = k0 + ty + 8*i, n = n0 + tx;
    tile[ty + 8*i][tx] = (k < K && n < N) ? Wz[(size_t)k * N + n] : 0.0f;
  }
  __syncthreads();
#pragma unroll
  for (int i = 0; i < 4; i++) {
    int n = n0 + ty + 8*i, k = k0 + tx;
    if (n < N && k < K) WTz[(size_t)n * K + k] = (bf16)tile[tx][ty + 8*i];
  }
}

// ---------------- bf16 MFMA GEMM: C[M,N] = A[M,K](f32) @ BT[N,K](bf16)^T ----
// mode 0: plain   1: +bias, gelu   2: +bias +resid
__global__ __launch_bounds__(256) void gemm_bf16(
    const float* __restrict__ A, const bf16* __restrict__ BT,
    float* __restrict__ C, int M, int N, int K,
    long strideAz, long strideBz, long strideCz, int flipz,
    int mode, const float* __restrict__ bias, const float* __restrict__ resid)
{
  int z = blockIdx.z;
  A  += (size_t)z * strideAz;
  BT += (size_t)z * strideBz;
  C  += (size_t)z * strideCz;
  int doflip = (flipz && z == 1);

  __shared__ __align__(16) bf16 As[128][40];
  __shared__ __align__(16) bf16 Bs[128][40];

  int m0 = blockIdx.x * 128, n0 = blockIdx.y * 128;
  int t = threadIdx.x;
  int lane = t & 63, w = t >> 6;
  int wr = w >> 1, wc = w & 1;
  int lr = lane & 15, lq = lane >> 4;

  int arow = t >> 1;
  int kg = (t & 1) * 16;
  int g_arow = m0 + arow;
  if (doflip) g_arow ^= 1023;
  const float* ap_base = A + (size_t)g_arow * K + kg;
  int gn = n0 + arow;
  const bf16* bp_base = (gn < N) ? (BT + (size_t)gn * K + kg) : nullptr;

  bf16 zb = (bf16)0.0f;
  f32x4 zf = {0.0f, 0.0f, 0.0f, 0.0f};
  f32x4 acc[4][4];
#pragma unroll
  for (int i = 0; i < 4; i++)
#pragma unroll
    for (int j = 0; j < 4; j++) acc[i][j] = zf;

  for (int k0 = 0; k0 < K; k0 += 32) {
    const float4* ap = (const float4*)(ap_base + k0);
    float4 v0 = ap[0], v1 = ap[1], v2 = ap[2], v3 = ap[3];
    bf16x8 lo, hi;
    lo[0]=(bf16)v0.x; lo[1]=(bf16)v0.y; lo[2]=(bf16)v0.z; lo[3]=(bf16)v0.w;
    lo[4]=(bf16)v1.x; lo[5]=(bf16)v1.y; lo[6]=(bf16)v1.z; lo[7]=(bf16)v1.w;
    hi[0]=(bf16)v2.x; hi[1]=(bf16)v2.y; hi[2]=(bf16)v2.z; hi[3]=(bf16)v2.w;
    hi[4]=(bf16)v3.x; hi[5]=(bf16)v3.y; hi[6]=(bf16)v3.z; hi[7]=(bf16)v3.w;

    bf16x8 b0 = {zb,zb,zb,zb,zb,zb,zb,zb}, b1 = b0;
    if (bp_base) {
      const bf16x8* bp = (const bf16x8*)(bp_base + k0);
      b0 = bp[0]; b1 = bp[1];
    }
    *(bf16x8*)&As[arow][kg]     = lo;
    *(bf16x8*)&As[arow][kg + 8] = hi;
    *(bf16x8*)&Bs[arow][kg]     = b0;
    *(bf16x8*)&Bs[arow][kg + 8] = b1;
    __syncthreads();

    bf16x8 af[4], bfv[4];
#pragma unroll
    for (int i = 0; i < 4; i++) af[i]  = *(const bf16x8*)&As[wr*64 + i*16 + lr][lq*8];
#pragma unroll
    for (int j = 0; j < 4; j++) bfv[j] = *(const bf16x8*)&Bs[wc*64 + j*16 + lr][lq*8];
#pragma unroll
    for (int i = 0; i < 4; i++)
#pragma unroll
      for (int j = 0; j < 4; j++)
        acc[i][j] = __builtin_amdgcn_mfma_f32_16x16x32_bf16(af[i], bfv[j], acc[i][j], 0, 0, 0);
    __syncthreads();
  }

#pragma unroll
  for (int i = 0; i < 4; i++) {
    int growb = m0 + wr*64 + i*16 + lq*4;
#pragma unroll
    for (int j = 0; j < 4; j++) {
      int gcol = n0 + wc*64 + j*16 + lr;
      if (gcol >= N) continue;
#pragma unroll
      for (int rr = 0; rr < 4; rr++) {
        int grow = growb + rr;
        float v = acc[i][j][rr];
        if (mode == 1) { v += bias[gcol]; v = 0.5f * v * (1.0f + erff(v * 0.70710678118f)); }
        else if (mode == 2) { v += bias[gcol] + resid[(size_t)grow * N + gcol]; }
        C[(size_t)grow * N + gcol] = v;
      }
    }
  }
}

// ---------------- conv(4-tap causal) + silu, plus dt/dA ----------------
__global__ __launch_bounds__(256) void convdt_kernel(
    const float* __restrict__ ZX, float* __restrict__ XBCC,
    float* __restrict__ DT, float* __restrict__ DA,
    const float* __restrict__ conv_w, const float* __restrict__ conv_b,
    const float* __restrict__ dt_bias, const float* __restrict__ A_log)
{
  int r = blockIdx.x;          // b*L + l
  int dir = blockIdx.y;
  int l = r & (L_SEQ - 1);
  int t = threadIdx.x;
  const float* zx = ZX + (size_t)dir * ROWS * DINPROJ;
  const float* cw = conv_w + (size_t)dir * CONVDIM * 4;
  const float* cb = conv_b + (size_t)dir * CONVDIM;
  float* xo = XBCC + ((size_t)dir * ROWS + r) * CONVDIM;

  for (int c = t; c < CONVDIM; c += 256) {
    float4 wv4 = *(const float4*)&cw[c * 4];
    const float* wv = (const float*)&wv4;
    float acc = cb[c];
#pragma unroll
    for (int k = 0; k < 4; k++) {
      int ls = l + k - 3;
      if (ls >= 0) acc += zx[(size_t)(r + k - 3) * DINPROJ + DINNER + c] * wv[k];
    }
    xo[c] = silu_f(acc);
  }
  if (t < NHEADS) {
    int h = t;
    float raw = zx[(size_t)r * DINPROJ + DINNER + CONVDIM + h] + dt_bias[dir * NHEADS + h];
    float dt = (raw > 20.0f) ? raw : log1pf(expf(raw));
    float A = -expf(A_log[dir * NHEADS + h]);
    size_t idx = ((size_t)dir * ROWS + r) * NHEADS + h;
    DT[idx] = dt;
    DA[idx] = expf(dt * A);
  }
}

// ---------------- sequential SSM scan: one wave per (dir,b,head) ----------
__global__ __launch_bounds__(64) void scan_kernel(
    const float* __restrict__ XBCC, const float* __restrict__ DT,
    const float* __restrict__ DA, float* __restrict__ YSSM)
{
  int bid = blockIdx.x;
  int dir = bid >> 5, rem = bid & 31;
  int b = rem >> 4, h = rem & 15;
  int lane = threadIdx.x;
  const float* xb  = XBCC + ((size_t)dir * ROWS + b * L_SEQ) * CONVDIM;
  const float* dtp = DT   + ((size_t)dir * ROWS + b * L_SEQ) * NHEADS + h;
  const float* dap = DA   + ((size_t)dir * ROWS + b * L_SEQ) * NHEADS + h;
  float* yp = YSSM + ((size_t)dir * ROWS + b * L_SEQ) * DINNER + h * HEADDIM + lane;

  float hs[16];
#pragma unroll
  for (int n = 0; n < 16; n++) hs[n] = 0.0f;

  for (int l = 0; l < L_SEQ; l++) {
    float dt = dtp[l * NHEADS];
    float da = dap[l * NHEADS];
    float xv = xb[(size_t)l * CONVDIM + h * HEADDIM + lane];
    const float4* q = (const float4*)(xb + (size_t)l * CONVDIM + DINNER);
    float Bv[16], Cv[16];
    *(float4*)&Bv[0]  = q[0]; *(float4*)&Bv[4]  = q[1];
    *(float4*)&Bv[8]  = q[2]; *(float4*)&Bv[12] = q[3];
    *(float4*)&Cv[0]  = q[4]; *(float4*)&Cv[4]  = q[5];
    *(float4*)&Cv[8]  = q[6]; *(float4*)&Cv[12] = q[7];
    float dtx = dt * xv;
    float acc = 0.0f;
#pragma unroll
    for (int n = 0; n < 16; n++) {
      hs[n] = hs[n] * da + dtx * Bv[n];
      acc += hs[n] * Cv[n];
    }
    yp[(size_t)l * DINNER] = acc;
  }
}

// ---------------- gate (D*xh, silu(z)) + RMS(1024, eps 1e-5) ----------------
__global__ __launch_bounds__(256) void gatenorm_kernel(
    float* __restrict__ YSSM, const float* __restrict__ XBCC,
    const float* __restrict__ ZX, const float* __restrict__ Dparam,
    const float* __restrict__ mnorm_w)
{
  int r = blockIdx.x, dir = blockIdx.y, t = threadIdx.x;
  float* y = YSSM + ((size_t)dir * ROWS + r) * DINNER;
  const float* xb = XBCC + ((size_t)dir * ROWS + r) * CONVDIM;
  const float* z  = ZX   + ((size_t)dir * ROWS + r) * DINPROJ;
  int c = t * 4;
  int h = c >> 6;
  float Dv = Dparam[dir * NHEADS + h];
  float4 yv = *(const float4*)&y[c];
  float4 xv = *(const float4*)&xb[c];
  float4 zv = *(const float4*)&z[c];
  float4 val;
  val.x = (yv.x + Dv*xv.x) * silu_f(zv.x);
  val.y = (yv.y + Dv*xv.y) * silu_f(zv.y);
  val.z = (yv.z + Dv*xv.z) * silu_f(zv.z);
  val.w = (yv.w + Dv*xv.w) * silu_f(zv.w);
  float ss = val.x*val.x + val.y*val.y + val.z*val.z + val.w*val.w;
  ss = wave_sum(ss);
  __shared__ float red[4];
  if ((t & 63) == 0) red[t >> 6] = ss;
  __syncthreads();
  float total = red[0] + red[1] + red[2] + red[3];
  float rs = 1.0f / sqrtf(total * (1.0f / DINNER) + 1e-5f);
  float4 wv = *(const float4*)&mnorm_w[dir * DINNER + c];
  val.x *= rs * wv.x; val.y *= rs * wv.y; val.z *= rs * wv.z; val.w *= rs * wv.w;
  *(float4*)&y[c] = val;
}

// ---------------- combine: x += 0.5*(fwd + flip(bwd))*mask ----------------
__global__ __launch_bounds__(128) void combine_kernel(
    float* __restrict__ X, const float* __restrict__ DOUT2,
    const float* __restrict__ mask)
{
  int r = blockIdx.x, t = threadIdx.x;
  int b = r >> 10, l = r & 1023;
  int c = t * 4;
  float m = 0.5f * mask[r];
  float4 f = *(const float4*)&DOUT2[(size_t)r * DMODEL + c];
  size_t br = (size_t)ROWS * DMODEL + ((size_t)(b * L_SEQ + (L_SEQ - 1 - l))) * DMODEL + c;
  float4 bw = *(const float4*)&DOUT2[br];
  float4 x = *(float4*)&X[(size_t)r * DMODEL + c];
  x.x += m * (f.x + bw.x);
  x.y += m * (f.y + bw.y);
  x.z += m * (f.z + bw.z);
  x.w += m * (f.w + bw.w);
  *(float4*)&X[(size_t)r * DMODEL + c] = x;
}

// ---------------- host ----------------
extern "C" void kernel_launch(void* const* d_in, const int* in_sizes, int n_in,
                              void* d_out, int out_size, void* d_ws, size_t ws_size,
                              hipStream_t stream)
{
  const float* in_x    = (const float*)d_in[0];
  const float* in_pe   = (const float*)d_in[1];
  const float* in_mask = (const float*)d_in[2];
  const float* W_in    = (const float*)d_in[3];
  const float* conv_w  = (const float*)d_in[4];
  const float* conv_b  = (const float*)d_in[5];
  const float* A_log   = (const float*)d_in[6];
  const float* Dparam  = (const float*)d_in[7];
  const float* dt_bias = (const float*)d_in[8];
  const float* mnorm_w = (const float*)d_in[9];
  const float* W_out   = (const float*)d_in[10];
  const float* nssm_w  = (const float*)d_in[11];
  const float* ffn_w1  = (const float*)d_in[12];
  const float* ffn_b1  = (const float*)d_in[13];
  const float* ffn_w2  = (const float*)d_in[14];
  const float* ffn_b2  = (const float*)d_in[15];
  const float* nffn_w  = (const float*)d_in[16];
  const float* final_w = (const float*)d_in[17];

  if (ws_size < 113082368) return;  // ws budget: see offsets below

  char* ws = (char*)d_ws;
  float* XBUF  = (float*)(ws + 0);          //  4,194,304   x state
  float* SBUF  = (float*)(ws + 4194304);    //  4,194,304   rms/scratch
  float* ZX    = (float*)(ws + 8388608);    // 34,340,864   in_proj out, 2 dirs
  float* XBCC  = (float*)(ws + 42729472);   // 17,301,504   conv+silu out
  float* DTb   = (float*)(ws + 60030976);   //    262,144
  float* DAb   = (float*)(ws + 60293120);   //    262,144
  float* YSSM  = (float*)(ws + 60555264);   // 16,777,216
  float* DOUT2 = (float*)(ws + 77332480);   //  8,388,608   per-dir out_proj
  float* MID   = (float*)(ws + 85721088);   // 16,777,216   ffn mid
  bf16*  WTIN  = (bf16*)(ws + 102498304);   //  4,292,608
  bf16*  WTOUT = (bf16*)(ws + 106790912);   //  2,097,152
  bf16*  WT1   = (bf16*)(ws + 108888064);   //  2,097,152
  bf16*  WT2   = (bf16*)(ws + 110985216);   //  2,097,152  end 113,082,368

  hipMemcpyAsync(XBUF, in_x, (size_t)ROWS * DMODEL * sizeof(float),
                 hipMemcpyDeviceToDevice, stream);

  for (int layer = 0; layer < 6; layer++) {
    // per-layer weight transpose+cvt (reused buffers keep ws small)
    transpose_cvt<<<dim3(16, 66, 2), 256, 0, stream>>>(
        W_in + (size_t)layer * 2 * DMODEL * DINPROJ, WTIN, DMODEL, DINPROJ);
    transpose_cvt<<<dim3(32, 16, 2), 256, 0, stream>>>(
        W_out + (size_t)layer * 2 * DINNER * DMODEL, WTOUT, DINNER, DMODEL);
    transpose_cvt<<<dim3(16, 64, 1), 256, 0, stream>>>(
        ffn_w1 + (size_t)layer * DMODEL * FFN_DIM, WT1, DMODEL, FFN_DIM);
    transpose_cvt<<<dim3(64, 16, 1), 256, 0, stream>>>(
        ffn_w2 + (size_t)layer * FFN_DIM * DMODEL, WT2, FFN_DIM, DMODEL);

    // s = (rms(x)*w + pe) * mask
    rms_kernel<<<ROWS, 128, 0, stream>>>(XBUF, nssm_w + layer * DMODEL,
                                         in_pe, in_mask, SBUF, 1e-6f);
    // in_proj, both dirs (z=1 reads A rows flipped: r^1023)
    gemm_bf16<<<dim3(16, 17, 2), 256, 0, stream>>>(
        SBUF, WTIN, ZX, ROWS, DINPROJ, DMODEL,
        0L, (long)DINPROJ * DMODEL, (long)ROWS * DINPROJ, 1, 0, nullptr, nullptr);
    convdt_kernel<<<dim3(ROWS, 2), 256, 0, stream>>>(
        ZX, XBCC, DTb, DAb,
        conv_w + (size_t)layer * 2 * CONVDIM * 4, conv_b + (size_t)layer * 2 * CONVDIM,
        dt_bias + layer * 2 * NHEADS, A_log + layer * 2 * NHEADS);
    scan_kernel<<<64, 64, 0, stream>>>(XBCC, DTb, DAb, YSSM);
    gatenorm_kernel<<<dim3(ROWS, 2), 256, 0, stream>>>(
        YSSM, XBCC, ZX, Dparam + layer * 2 * NHEADS, mnorm_w + layer * 2 * DINNER);
    gemm_bf16<<<dim3(16, 4, 2), 256, 0, stream>>>(
        YSSM, WTOUT, DOUT2, ROWS, DMODEL, DINNER,
        (long)ROWS * DINNER, (long)DMODEL * DINNER, (long)ROWS * DMODEL, 0, 0,
        nullptr, nullptr);
    combine_kernel<<<ROWS, 128, 0, stream>>>(XBUF, DOUT2, in_mask);

    // FFN
    rms_kernel<<<ROWS, 128, 0, stream>>>(XBUF, nffn_w + layer * DMODEL,
                                         nullptr, nullptr, SBUF, 1e-6f);
    gemm_bf16<<<dim3(16, 16, 1), 256, 0, stream>>>(
        SBUF, WT1, MID, ROWS, FFN_DIM, DMODEL,
        0L, 0L, 0L, 0, 1, ffn_b1 + layer * FFN_DIM, nullptr);
    gemm_bf16<<<dim3(16, 4, 1), 256, 0, stream>>>(
        MID, WT2, XBUF, ROWS, DMODEL, FFN_DIM,
        0L, 0L, 0L, 0, 2, ffn_b2 + layer * DMODEL, XBUF);
  }
  rms_kernel<<<ROWS, 128, 0, stream>>>(XBUF, final_w, nullptr, nullptr,
                                       (float*)d_out, 1e-6f);
}

// Round 2
// 1868.582 us; speedup vs baseline: 2.0653x; 2.0653x over previous
//
#include <hip/hip_runtime.h>
#include <cstdint>
#include <cstddef>

typedef __bf16 bf16;
typedef __bf16 bf16x8 __attribute__((ext_vector_type(8)));
typedef float f32x4 __attribute__((ext_vector_type(4)));

#define L_SEQ   1024
#define DMODEL  512
#define DINNER  1024
#define DSTATE  16
#define NHEADS  16
#define HEADDIM 64
#define CONVDIM 1056
#define DINPROJ 2096
#define FFN_DIM 2048
#define ROWS    2048   // B*L
#define CHUNK   64
#define NCHUNK  16     // L_SEQ / CHUNK

__device__ __forceinline__ float wave_sum(float v) {
#pragma unroll
  for (int off = 32; off; off >>= 1) v += __shfl_down(v, off, 64);
  return v;
}

__device__ __forceinline__ float silu_f(float x) { return x / (1.0f + expf(-x)); }

// ---------------- RMS norm (+ optional pe/mask), C = 512 ----------------
__global__ __launch_bounds__(128) void rms_kernel(
    const float* __restrict__ x, const float* __restrict__ w,
    const float* __restrict__ pe, const float* __restrict__ mask,
    float* __restrict__ out, float eps)
{
  int r = blockIdx.x;
  int t = threadIdx.x;
  float4 v = ((const float4*)(x + (size_t)r * DMODEL))[t];
  float ss = v.x*v.x + v.y*v.y + v.z*v.z + v.w*v.w;
  ss = wave_sum(ss);
  __shared__ float red[2];
  if ((t & 63) == 0) red[t >> 6] = ss;
  __syncthreads();
  float total = red[0] + red[1];
  float rs = 1.0f / sqrtf(total * (1.0f / DMODEL) + eps);
  float4 wv = ((const float4*)w)[t];
  float4 o;
  o.x = v.x*rs*wv.x; o.y = v.y*rs*wv.y; o.z = v.z*rs*wv.z; o.w = v.w*rs*wv.w;
  if (pe) {
    float4 p = ((const float4*)(pe + (size_t)r * DMODEL))[t];
    float m = mask[r];
    o.x = (o.x + p.x)*m; o.y = (o.y + p.y)*m; o.z = (o.z + p.z)*m; o.w = (o.w + p.w)*m;
  }
  ((float4*)(out + (size_t)r * DMODEL))[t] = o;
}

// ---------------- transpose + f32->bf16: WT[n][k] = W[k][n] ----------------
__global__ __launch_bounds__(256) void transpose_cvt(
    const float* __restrict__ W, bf16* __restrict__ WT, int K, int N)
{
  __shared__ float tile[32][33];
  int z = blockIdx.z;
  const float* Wz = W + (size_t)z * K * N;
  bf16* WTz = WT + (size_t)z * N * K;
  int k0 = blockIdx.x * 32, n0 = blockIdx.y * 32;
  int tx = threadIdx.x & 31, ty = threadIdx.x >> 5;
#pragma unroll
  for (int i = 0; i < 4; i++) {
    int k = k0 + ty + 8*i, n = n0 + tx;
    tile[ty + 8*i][tx] = (k < K && n < N) ? Wz[(size_t)k * N + n] : 0.0f;
  }
  __syncthreads();
#pragma unroll
  for (int i = 0; i < 4; i++) {
    int n = n0 + ty + 8*i, k = k0 + tx;
    if (n < N && k < K) WTz[(size_t)n * K + k] = (bf16)tile[tx][ty + 8*i];
  }
}

// ---------------- bf16 MFMA GEMM: C[M,N] = A[M,K](f32) @ BT[N,K](bf16)^T ----
// mode 0: plain   1: +bias, gelu   2: +bias +resid
__global__ __launch_bounds__(256) void gemm_bf16(
    const float* __restrict__ A, const bf16* __restrict__ BT,
    float* __restrict__ C, int M, int N, int K,
    long strideAz, long strideBz, long strideCz, int flipz,
    int mode, const float* __restrict__ bias, const float* __restrict__ resid)
{
  int z = blockIdx.z;
  A  += (size_t)z * strideAz;
  BT += (size_t)z * strideBz;
  C  += (size_t)z * strideCz;
  int doflip = (flipz && z == 1);

  __shared__ __align__(16) bf16 As[128][40];
  __shared__ __align__(16) bf16 Bs[128][40];

  int m0 = blockIdx.x * 128, n0 = blockIdx.y * 128;
  int t = threadIdx.x;
  int lane = t & 63, w = t >> 6;
  int wr = w >> 1, wc = w & 1;
  int lr = lane & 15, lq = lane >> 4;

  int arow = t >> 1;
  int kg = (t & 1) * 16;
  int g_arow = m0 + arow;
  if (doflip) g_arow ^= 1023;
  const float* ap_base = A + (size_t)g_arow * K + kg;
  int gn = n0 + arow;
  const bf16* bp_base = (gn < N) ? (BT + (size_t)gn * K + kg) : nullptr;

  bf16 zb = (bf16)0.0f;
  f32x4 zf = {0.0f, 0.0f, 0.0f, 0.0f};
  f32x4 acc[4][4];
#pragma unroll
  for (int i = 0; i < 4; i++)
#pragma unroll
    for (int j = 0; j < 4; j++) acc[i][j] = zf;

  for (int k0 = 0; k0 < K; k0 += 32) {
    const float4* ap = (const float4*)(ap_base + k0);
    float4 v0 = ap[0], v1 = ap[1], v2 = ap[2], v3 = ap[3];
    bf16x8 lo, hi;
    lo[0]=(bf16)v0.x; lo[1]=(bf16)v0.y; lo[2]=(bf16)v0.z; lo[3]=(bf16)v0.w;
    lo[4]=(bf16)v1.x; lo[5]=(bf16)v1.y; lo[6]=(bf16)v1.z; lo[7]=(bf16)v1.w;
    hi[0]=(bf16)v2.x; hi[1]=(bf16)v2.y; hi[2]=(bf16)v2.z; hi[3]=(bf16)v2.w;
    hi[4]=(bf16)v3.x; hi[5]=(bf16)v3.y; hi[6]=(bf16)v3.z; hi[7]=(bf16)v3.w;

    bf16x8 b0 = {zb,zb,zb,zb,zb,zb,zb,zb}, b1 = b0;
    if (bp_base) {
      const bf16x8* bp = (const bf16x8*)(bp_base + k0);
      b0 = bp[0]; b1 = bp[1];
    }
    *(bf16x8*)&As[arow][kg]     = lo;
    *(bf16x8*)&As[arow][kg + 8] = hi;
    *(bf16x8*)&Bs[arow][kg]     = b0;
    *(bf16x8*)&Bs[arow][kg + 8] = b1;
    __syncthreads();

    bf16x8 af[4], bfv[4];
#pragma unroll
    for (int i = 0; i < 4; i++) af[i]  = *(const bf16x8*)&As[wr*64 + i*16 + lr][lq*8];
#pragma unroll
    for (int j = 0; j < 4; j++) bfv[j] = *(const bf16x8*)&Bs[wc*64 + j*16 + lr][lq*8];
#pragma unroll
    for (int i = 0; i < 4; i++)
#pragma unroll
      for (int j = 0; j < 4; j++)
        acc[i][j] = __builtin_amdgcn_mfma_f32_16x16x32_bf16(af[i], bfv[j], acc[i][j], 0, 0, 0);
    __syncthreads();
  }

#pragma unroll
  for (int i = 0; i < 4; i++) {
    int growb = m0 + wr*64 + i*16 + lq*4;
#pragma unroll
    for (int j = 0; j < 4; j++) {
      int gcol = n0 + wc*64 + j*16 + lr;
      if (gcol >= N) continue;
#pragma unroll
      for (int rr = 0; rr < 4; rr++) {
        int grow = growb + rr;
        float v = acc[i][j][rr];
        if (mode == 1) { v += bias[gcol]; v = 0.5f * v * (1.0f + erff(v * 0.70710678118f)); }
        else if (mode == 2) { v += bias[gcol] + resid[(size_t)grow * N + gcol]; }
        C[(size_t)grow * N + gcol] = v;
      }
    }
  }
}

// ---------------- conv(4-tap causal) + silu, plus dt/dA ----------------
__global__ __launch_bounds__(256) void convdt_kernel(
    const float* __restrict__ ZX, float* __restrict__ XBCC,
    float* __restrict__ DT, float* __restrict__ DA,
    const float* __restrict__ conv_w, const float* __restrict__ conv_b,
    const float* __restrict__ dt_bias, const float* __restrict__ A_log)
{
  int r = blockIdx.x;          // b*L + l
  int dir = blockIdx.y;
  int l = r & (L_SEQ - 1);
  int t = threadIdx.x;
  const float* zx = ZX + (size_t)dir * ROWS * DINPROJ;
  const float* cw = conv_w + (size_t)dir * CONVDIM * 4;
  const float* cb = conv_b + (size_t)dir * CONVDIM;
  float* xo = XBCC + ((size_t)dir * ROWS + r) * CONVDIM;

  for (int c = t; c < CONVDIM; c += 256) {
    float4 wv4 = *(const float4*)&cw[c * 4];
    const float* wv = (const float*)&wv4;
    float acc = cb[c];
#pragma unroll
    for (int k = 0; k < 4; k++) {
      int ls = l + k - 3;
      if (ls >= 0) acc += zx[(size_t)(r + k - 3) * DINPROJ + DINNER + c] * wv[k];
    }
    xo[c] = silu_f(acc);
  }
  if (t < NHEADS) {
    int h = t;
    float raw = zx[(size_t)r * DINPROJ + DINNER + CONVDIM + h] + dt_bias[dir * NHEADS + h];
    float dt = (raw > 20.0f) ? raw : log1pf(expf(raw));
    float A = -expf(A_log[dir * NHEADS + h]);
    size_t idx = ((size_t)dir * ROWS + r) * NHEADS + h;
    DT[idx] = dt;
    DA[idx] = expf(dt * A);
  }
}

// ---------------- chunked SSM scan, pass 1: local scans ----------------
// grid = 64 groups (dir,b,h) x 16 chunks = 1024 blocks of 1 wave
__global__ __launch_bounds__(64) void scan1_kernel(
    const float* __restrict__ XBCC, const float* __restrict__ DT,
    const float* __restrict__ DA, float* __restrict__ YSSM,
    float* __restrict__ HEND, float* __restrict__ APROD)
{
  int bid = blockIdx.x;
  int g = bid >> 4, c = bid & 15;
  int dir = g >> 5, rem = g & 31;
  int b = rem >> 4, h = rem & 15;
  int lane = threadIdx.x;
  size_t rowbase = (size_t)dir * ROWS + b * L_SEQ + c * CHUNK;
  const float* xb = XBCC + rowbase * CONVDIM;

  // per-lane dt/da for timestep l = lane
  float dtv = DT[(rowbase + lane) * NHEADS + h];
  float dav = DA[(rowbase + lane) * NHEADS + h];

  // inclusive cumulative product of da across lanes (shfl-scan)
  float ap = dav;
#pragma unroll
  for (int off = 1; off < 64; off <<= 1) {
    float o = __shfl_up(ap, off, 64);
    if (lane >= off) ap *= o;
  }
  APROD[((size_t)g * NCHUNK + c) * 64 + lane] = ap;

  // stage B (16) + C (16) per timestep into LDS; padded stride 36
  __shared__ float BCs[CHUNK][36];
#pragma unroll
  for (int i = 0; i < 8; i++) {
    int l = i * 8 + (lane >> 3), f = lane & 7;
    float4 v = *(const float4*)&xb[(size_t)l * CONVDIM + DINNER + f * 4];
    *(float4*)&BCs[l][f * 4] = v;
  }
  __syncthreads();

  float hs[16];
#pragma unroll
  for (int n = 0; n < 16; n++) hs[n] = 0.0f;

  const float* xp = xb + h * HEADDIM + lane;
  float* yp = YSSM + rowbase * DINNER + h * HEADDIM + lane;

  for (int l = 0; l < CHUNK; l++) {
    float dt = __shfl(dtv, l, 64);
    float da = __shfl(dav, l, 64);
    float xv = xp[(size_t)l * CONVDIM];
    float4 bq[4], cq[4];
#pragma unroll
    for (int q = 0; q < 4; q++) {
      bq[q] = *(const float4*)&BCs[l][q * 4];
      cq[q] = *(const float4*)&BCs[l][16 + q * 4];
    }
    const float* Bv = (const float*)bq;
    const float* Cv = (const float*)cq;
    float dtx = dt * xv;
    float acc = 0.0f;
#pragma unroll
    for (int n = 0; n < 16; n++) {
      hs[n] = hs[n] * da + dtx * Bv[n];
      acc += hs[n] * Cv[n];
    }
    yp[(size_t)l * DINNER] = acc;
  }

  // store chunk-end local state: HEND[g][c][n][p]
  float* he = HEND + ((size_t)g * NCHUNK + c) * 16 * 64;
#pragma unroll
  for (int n = 0; n < 16; n++) he[n * 64 + lane] = hs[n];
}

// ---------------- chunked SSM scan, pass 2: cross-chunk correction --------
__global__ __launch_bounds__(64) void scan2_kernel(
    const float* __restrict__ XBCC, float* __restrict__ YSSM,
    const float* __restrict__ HEND, const float* __restrict__ APROD)
{
  int bid = blockIdx.x;
  int g = bid >> 4, c = bid & 15;
  if (c == 0) return;
  int dir = g >> 5, rem = g & 31;
  int b = rem >> 4, h = rem & 15;
  int lane = threadIdx.x;

  // h_start(c) = sum_{j<c} (prod_{i=j+1..c-1} P_i) * E_j ; P_j = APROD[j][63]
  float hstart[16];
#pragma unroll
  for (int n = 0; n < 16; n++) hstart[n] = 0.0f;
  float w = 1.0f;
  for (int j = c - 1; j >= 0; j--) {
    const float* he = HEND + ((size_t)g * NCHUNK + j) * 16 * 64;
#pragma unroll
    for (int n = 0; n < 16; n++) hstart[n] += w * he[n * 64 + lane];
    w *= APROD[((size_t)g * NCHUNK + j) * 64 + 63];
  }

  size_t rowbase = (size_t)dir * ROWS + b * L_SEQ + c * CHUNK;
  const float* xb = XBCC + rowbase * CONVDIM;
  float* yp = YSSM + rowbase * DINNER + h * HEADDIM + lane;
  float apv = APROD[((size_t)g * NCHUNK + c) * 64 + lane];

  // stage C into LDS (16 per timestep), padded stride 20
  __shared__ float Cs[CHUNK][20];
#pragma unroll
  for (int i = 0; i < 4; i++) {
    int l = i * 16 + (lane >> 2), f = lane & 3;
    float4 v = *(const float4*)&xb[(size_t)l * CONVDIM + DINNER + 16 + f * 4];
    *(float4*)&Cs[l][f * 4] = v;
  }
  __syncthreads();

  for (int l = 0; l < CHUNK; l++) {
    float a = __shfl(apv, l, 64);
    float4 cq[4];
#pragma unroll
    for (int q = 0; q < 4; q++) cq[q] = *(const float4*)&Cs[l][q * 4];
    const float* Cv = (const float*)cq;
    float acc = 0.0f;
#pragma unroll
    for (int n = 0; n < 16; n++) acc += Cv[n] * hstart[n];
    yp[(size_t)l * DINNER] += a * acc;
  }
}

// ---------------- gate (D*xh, silu(z)) + RMS(1024, eps 1e-5) ----------------
__global__ __launch_bounds__(256) void gatenorm_kernel(
    float* __restrict__ YSSM, const float* __restrict__ XBCC,
    const float* __restrict__ ZX, const float* __restrict__ Dparam,
    const float* __restrict__ mnorm_w)
{
  int r = blockIdx.x, dir = blockIdx.y, t = threadIdx.x;
  float* y = YSSM + ((size_t)dir * ROWS + r) * DINNER;
  const float* xb = XBCC + ((size_t)dir * ROWS + r) * CONVDIM;
  const float* z  = ZX   + ((size_t)dir * ROWS + r) * DINPROJ;
  int c = t * 4;
  int h = c >> 6;
  float Dv = Dparam[dir * NHEADS + h];
  float4 yv = *(const float4*)&y[c];
  float4 xv = *(const float4*)&xb[c];
  float4 zv = *(const float4*)&z[c];
  float4 val;
  val.x = (yv.x + Dv*xv.x) * silu_f(zv.x);
  val.y = (yv.y + Dv*xv.y) * silu_f(zv.y);
  val.z = (yv.z + Dv*xv.z) * silu_f(zv.z);
  val.w = (yv.w + Dv*xv.w) * silu_f(zv.w);
  float ss = val.x*val.x + val.y*val.y + val.z*val.z + val.w*val.w;
  ss = wave_sum(ss);
  __shared__ float red[4];
  if ((t & 63) == 0) red[t >> 6] = ss;
  __syncthreads();
  float total = red[0] + red[1] + red[2] + red[3];
  float rs = 1.0f / sqrtf(total * (1.0f / DINNER) + 1e-5f);
  float4 wv = *(const float4*)&mnorm_w[dir * DINNER + c];
  val.x *= rs * wv.x; val.y *= rs * wv.y; val.z *= rs * wv.z; val.w *= rs * wv.w;
  *(float4*)&y[c] = val;
}

// ---------------- combine: x += 0.5*(fwd + flip(bwd))*mask ----------------
__global__ __launch_bounds__(128) void combine_kernel(
    float* __restrict__ X, const float* __restrict__ DOUT2,
    const float* __restrict__ mask)
{
  int r = blockIdx.x, t = threadIdx.x;
  int b = r >> 10, l = r & 1023;
  int c = t * 4;
  float m = 0.5f * mask[r];
  float4 f = *(const float4*)&DOUT2[(size_t)r * DMODEL + c];
  size_t br = (size_t)ROWS * DMODEL + ((size_t)(b * L_SEQ + (L_SEQ - 1 - l))) * DMODEL + c;
  float4 bw = *(const float4*)&DOUT2[br];
  float4 x = *(float4*)&X[(size_t)r * DMODEL + c];
  x.x += m * (f.x + bw.x);
  x.y += m * (f.y + bw.y);
  x.z += m * (f.z + bw.z);
  x.w += m * (f.w + bw.w);
  *(float4*)&X[(size_t)r * DMODEL + c] = x;
}

// ---------------- host ----------------
extern "C" void kernel_launch(void* const* d_in, const int* in_sizes, int n_in,
                              void* d_out, int out_size, void* d_ws, size_t ws_size,
                              hipStream_t stream)
{
  const float* in_x    = (const float*)d_in[0];
  const float* in_pe   = (const float*)d_in[1];
  const float* in_mask = (const float*)d_in[2];
  const float* W_in    = (const float*)d_in[3];
  const float* conv_w  = (const float*)d_in[4];
  const float* conv_b  = (const float*)d_in[5];
  const float* A_log   = (const float*)d_in[6];
  const float* Dparam  = (const float*)d_in[7];
  const float* dt_bias = (const float*)d_in[8];
  const float* mnorm_w = (const float*)d_in[9];
  const float* W_out   = (const float*)d_in[10];
  const float* nssm_w  = (const float*)d_in[11];
  const float* ffn_w1  = (const float*)d_in[12];
  const float* ffn_b1  = (const float*)d_in[13];
  const float* ffn_w2  = (const float*)d_in[14];
  const float* ffn_b2  = (const float*)d_in[15];
  const float* nffn_w  = (const float*)d_in[16];
  const float* final_w = (const float*)d_in[17];

  if (ws_size < 113082368) return;  // ws budget: see offsets below

  char* ws = (char*)d_ws;
  float* XBUF  = (float*)(ws + 0);          //  4,194,304   x state
  float* SBUF  = (float*)(ws + 4194304);    //  4,194,304   rms/scratch
  float* ZX    = (float*)(ws + 8388608);    // 34,340,864   in_proj out, 2 dirs
  float* XBCC  = (float*)(ws + 42729472);   // 17,301,504   conv+silu out
  float* DTb   = (float*)(ws + 60030976);   //    262,144
  float* DAb   = (float*)(ws + 60293120);   //    262,144
  float* YSSM  = (float*)(ws + 60555264);   // 16,777,216
  float* DOUT2 = (float*)(ws + 77332480);   //  8,388,608   per-dir out_proj
  float* MID   = (float*)(ws + 85721088);   // 16,777,216   ffn mid
  bf16*  WTIN  = (bf16*)(ws + 102498304);   //  4,292,608
  bf16*  WTOUT = (bf16*)(ws + 106790912);   //  2,097,152
  bf16*  WT1   = (bf16*)(ws + 108888064);   //  2,097,152
  bf16*  WT2   = (bf16*)(ws + 110985216);   //  2,097,152  end 113,082,368

  // scan scratch aliases MID (dead during scan phase):
  float* HEND  = MID;                                    // 4,194,304
  float* APROD = (float*)(ws + 85721088 + 4194304);      //   262,144

  hipMemcpyAsync(XBUF, in_x, (size_t)ROWS * DMODEL * sizeof(float),
                 hipMemcpyDeviceToDevice, stream);

  for (int layer = 0; layer < 6; layer++) {
    // per-layer weight transpose+cvt (reused buffers keep ws small)
    transpose_cvt<<<dim3(16, 66, 2), 256, 0, stream>>>(
        W_in + (size_t)layer * 2 * DMODEL * DINPROJ, WTIN, DMODEL, DINPROJ);
    transpose_cvt<<<dim3(32, 16, 2), 256, 0, stream>>>(
        W_out + (size_t)layer * 2 * DINNER * DMODEL, WTOUT, DINNER, DMODEL);
    transpose_cvt<<<dim3(16, 64, 1), 256, 0, stream>>>(
        ffn_w1 + (size_t)layer * DMODEL * FFN_DIM, WT1, DMODEL, FFN_DIM);
    transpose_cvt<<<dim3(64, 16, 1), 256, 0, stream>>>(
        ffn_w2 + (size_t)layer * FFN_DIM * DMODEL, WT2, FFN_DIM, DMODEL);

    // s = (rms(x)*w + pe) * mask
    rms_kernel<<<ROWS, 128, 0, stream>>>(XBUF, nssm_w + layer * DMODEL,
                                         in_pe, in_mask, SBUF, 1e-6f);
    // in_proj, both dirs (z=1 reads A rows flipped: r^1023)
    gemm_bf16<<<dim3(16, 17, 2), 256, 0, stream>>>(
        SBUF, WTIN, ZX, ROWS, DINPROJ, DMODEL,
        0L, (long)DINPROJ * DMODEL, (long)ROWS * DINPROJ, 1, 0, nullptr, nullptr);
    convdt_kernel<<<dim3(ROWS, 2), 256, 0, stream>>>(
        ZX, XBCC, DTb, DAb,
        conv_w + (size_t)layer * 2 * CONVDIM * 4, conv_b + (size_t)layer * 2 * CONVDIM,
        dt_bias + layer * 2 * NHEADS, A_log + layer * 2 * NHEADS);
    scan1_kernel<<<1024, 64, 0, stream>>>(XBCC, DTb, DAb, YSSM, HEND, APROD);
    scan2_kernel<<<1024, 64, 0, stream>>>(XBCC, YSSM, HEND, APROD);
    gatenorm_kernel<<<dim3(ROWS, 2), 256, 0, stream>>>(
        YSSM, XBCC, ZX, Dparam + layer * 2 * NHEADS, mnorm_w + layer * 2 * DINNER);
    gemm_bf16<<<dim3(16, 4, 2), 256, 0, stream>>>(
        YSSM, WTOUT, DOUT2, ROWS, DMODEL, DINNER,
        (long)ROWS * DINNER, (long)DMODEL * DINNER, (long)ROWS * DMODEL, 0, 0,
        nullptr, nullptr);
    combine_kernel<<<ROWS, 128, 0, stream>>>(XBUF, DOUT2, in_mask);

    // FFN
    rms_kernel<<<ROWS, 128, 0, stream>>>(XBUF, nffn_w + layer * DMODEL,
                                         nullptr, nullptr, SBUF, 1e-6f);
    gemm_bf16<<<dim3(16, 16, 1), 256, 0, stream>>>(
        SBUF, WT1, MID, ROWS, FFN_DIM, DMODEL,
        0L, 0L, 0L, 0, 1, ffn_b1 + layer * FFN_DIM, nullptr);
    gemm_bf16<<<dim3(16, 4, 1), 256, 0, stream>>>(
        MID, WT2, XBUF, ROWS, DMODEL, FFN_DIM,
        0L, 0L, 0L, 0, 2, ffn_b2 + layer * DMODEL, XBUF);
  }
  rms_kernel<<<ROWS, 128, 0, stream>>>(XBUF, final_w, nullptr, nullptr,
                                       (float*)d_out, 1e-6f);
}

// Round 3
// 1324.609 us; speedup vs baseline: 2.9134x; 1.4107x over previous
//
#include <hip/hip_runtime.h>
#include <cstdint>
#include <cstddef>

typedef __bf16 bf16;
typedef __bf16 bf16x8 __attribute__((ext_vector_type(8)));
typedef float f32x4 __attribute__((ext_vector_type(4)));

#define L_SEQ   1024
#define DMODEL  512
#define DINNER  1024
#define DSTATE  16
#define NHEADS  16
#define HEADDIM 64
#define CONVDIM 1056
#define DINPROJ 2096
#define FFN_DIM 2048
#define ROWS    2048   // B*L
#define CHUNK   64
#define NCHUNK  16     // L_SEQ / CHUNK

__device__ __forceinline__ float wave_sum(float v) {
#pragma unroll
  for (int off = 32; off; off >>= 1) v += __shfl_down(v, off, 64);
  return v;
}

__device__ __forceinline__ float silu_f(float x) { return x / (1.0f + expf(-x)); }

// ---------------- RMS norm (+ optional pe/mask), C = 512 ----------------
// outb != null -> bf16 output, else f32 to outf
__global__ __launch_bounds__(128) void rms_kernel(
    const float* __restrict__ x, const float* __restrict__ w,
    const float* __restrict__ pe, const float* __restrict__ mask,
    float* __restrict__ outf, bf16* __restrict__ outb, float eps)
{
  int r = blockIdx.x;
  int t = threadIdx.x;
  float4 v = ((const float4*)(x + (size_t)r * DMODEL))[t];
  float ss = v.x*v.x + v.y*v.y + v.z*v.z + v.w*v.w;
  ss = wave_sum(ss);
  __shared__ float red[2];
  if ((t & 63) == 0) red[t >> 6] = ss;
  __syncthreads();
  float total = red[0] + red[1];
  float rs = 1.0f / sqrtf(total * (1.0f / DMODEL) + eps);
  float4 wv = ((const float4*)w)[t];
  float4 o;
  o.x = v.x*rs*wv.x; o.y = v.y*rs*wv.y; o.z = v.z*rs*wv.z; o.w = v.w*rs*wv.w;
  if (pe) {
    float4 p = ((const float4*)(pe + (size_t)r * DMODEL))[t];
    float m = mask[r];
    o.x = (o.x + p.x)*m; o.y = (o.y + p.y)*m; o.z = (o.z + p.z)*m; o.w = (o.w + p.w)*m;
  }
  if (outb) {
    bf16 o4[4] = {(bf16)o.x, (bf16)o.y, (bf16)o.z, (bf16)o.w};
    *(uint2*)&outb[(size_t)r * DMODEL + t * 4] = *(uint2*)o4;
  } else {
    ((float4*)(outf + (size_t)r * DMODEL))[t] = o;
  }
}

// ---------------- transpose + f32->bf16: WT[n][k] = W[k][n] ----------------
__global__ __launch_bounds__(256) void transpose_cvt(
    const float* __restrict__ W, bf16* __restrict__ WT, int K, int N)
{
  __shared__ float tile[32][33];
  int z = blockIdx.z;
  const float* Wz = W + (size_t)z * K * N;
  bf16* WTz = WT + (size_t)z * N * K;
  int k0 = blockIdx.x * 32, n0 = blockIdx.y * 32;
  int tx = threadIdx.x & 31, ty = threadIdx.x >> 5;
#pragma unroll
  for (int i = 0; i < 4; i++) {
    int k = k0 + ty + 8*i, n = n0 + tx;
    tile[ty + 8*i][tx] = (k < K && n < N) ? Wz[(size_t)k * N + n] : 0.0f;
  }
  __syncthreads();
#pragma unroll
  for (int i = 0; i < 4; i++) {
    int n = n0 + ty + 8*i, k = k0 + tx;
    if (n < N && k < K) WTz[(size_t)n * K + k] = (bf16)tile[tx][ty + 8*i];
  }
}

// ---------------- bf16 MFMA GEMM, global_load_lds staging -------------------
// C[M,N] = A[M,K](bf16, row-major, stride lda) @ BT[N,K](bf16)^T
// MODE 0: f32 out   MODE 1: +bias, gelu, bf16 out
template<int BM, int BN, int FI, int FJ, int MODE>
__global__ __launch_bounds__(256) void gemm_tile(
    const bf16* __restrict__ A, const bf16* __restrict__ BT,
    float* __restrict__ Cf, bf16* __restrict__ Cb,
    int M, int N, int K, int lda, int ldb,
    long aOffz, long bOffz, long cOffz, int flipz,
    const float* __restrict__ bias)
{
  constexpr int TG = (BM + BN) * 4;   // 16-byte granules per K-step
  constexpr int NI = TG / 256;        // global_load_lds issues per wave

  int z = blockIdx.z;
  A  += (size_t)z * aOffz;
  BT += (size_t)z * bOffz;
  long coff = (size_t)z * cOffz;
  int doflip = (flipz && z == 1);

  __shared__ __align__(16) bf16 Tile[(BM + BN) * 32];
  bf16* As = Tile;
  bf16* Bs = Tile + BM * 32;

  int m0 = blockIdx.x * BM, n0 = blockIdx.y * BN;
  int t = threadIdx.x;
  int lane = t & 63, w = t >> 6;
  int wr = w >> 1, wc = w & 1;
  int lr = lane & 15, lq = lane >> 4;

  // per-lane global source for each staging issue
  const bf16* gsrc[NI];
#pragma unroll
  for (int i = 0; i < NI; i++) {
    int g = w * (TG / 4) + i * 64 + lane;
    if (g < BM * 4) {
      int row = g >> 2, kp = g & 3;
      int gr = m0 + row;
      if (doflip) gr ^= (L_SEQ - 1);
      gsrc[i] = A + (size_t)gr * lda + kp * 8;
    } else {
      int g2 = g - BM * 4;
      int row = g2 >> 2, kp = g2 & 3;
      int gn = n0 + row; if (gn >= N) gn = N - 1;
      gsrc[i] = BT + (size_t)gn * ldb + kp * 8;
    }
  }

  f32x4 zf = {0.0f, 0.0f, 0.0f, 0.0f};
  f32x4 acc[FI][FJ];
#pragma unroll
  for (int i = 0; i < FI; i++)
#pragma unroll
    for (int j = 0; j < FJ; j++) acc[i][j] = zf;

  for (int k0 = 0; k0 < K; k0 += 32) {
#pragma unroll
    for (int i = 0; i < NI; i++) {
      int chunk = w * (TG / 4) + i * 64;   // wave-uniform granule base
      __builtin_amdgcn_global_load_lds(
          (const __attribute__((address_space(1))) void*)(gsrc[i] + k0),
          (__attribute__((address_space(3))) void*)&Tile[chunk * 8],
          16, 0, 0);
    }
    __syncthreads();

    bf16x8 af[FI], bfv[FJ];
#pragma unroll
    for (int i = 0; i < FI; i++)
      af[i] = *(const bf16x8*)&As[(wr * 64 + i * 16 + lr) * 32 + lq * 8];
#pragma unroll
    for (int j = 0; j < FJ; j++)
      bfv[j] = *(const bf16x8*)&Bs[(wc * (BN / 2) + j * 16 + lr) * 32 + lq * 8];
#pragma unroll
    for (int i = 0; i < FI; i++)
#pragma unroll
      for (int j = 0; j < FJ; j++)
        acc[i][j] = __builtin_amdgcn_mfma_f32_16x16x32_bf16(af[i], bfv[j], acc[i][j], 0, 0, 0);
    __syncthreads();
  }

#pragma unroll
  for (int i = 0; i < FI; i++) {
    int growb = m0 + wr * 64 + i * 16 + lq * 4;
#pragma unroll
    for (int j = 0; j < FJ; j++) {
      int gcol = n0 + wc * (BN / 2) + j * 16 + lr;
      if (gcol >= N) continue;
#pragma unroll
      for (int rr = 0; rr < 4; rr++) {
        int grow = growb + rr;
        float v = acc[i][j][rr];
        if (MODE == 1) {
          v += bias[gcol];
          v = 0.5f * v * (1.0f + erff(v * 0.70710678118f));
          Cb[coff + (size_t)grow * N + gcol] = (bf16)v;
        } else {
          Cf[coff + (size_t)grow * N + gcol] = v;
        }
      }
    }
  }
}

// ---------------- FFN2 split-K reduce + bias + residual ----------------
__global__ __launch_bounds__(128) void ffn2_reduce(
    float* __restrict__ X, const float* __restrict__ P,
    const float* __restrict__ bias)
{
  int r = blockIdx.x, t = threadIdx.x;
  int c = t * 4;
  float4 a = *(const float4*)&P[(size_t)r * DMODEL + c];
  float4 b = *(const float4*)&P[(size_t)ROWS * DMODEL + (size_t)r * DMODEL + c];
  float4 bi = *(const float4*)&bias[c];
  float4 x = *(float4*)&X[(size_t)r * DMODEL + c];
  x.x += a.x + b.x + bi.x;
  x.y += a.y + b.y + bi.y;
  x.z += a.z + b.z + bi.z;
  x.w += a.w + b.w + bi.w;
  *(float4*)&X[(size_t)r * DMODEL + c] = x;
}

// ---------------- conv(4-tap causal) + silu, plus dt/dA ----------------
__global__ __launch_bounds__(256) void convdt_kernel(
    const float* __restrict__ ZX, float* __restrict__ XBCC,
    float* __restrict__ DT, float* __restrict__ DA,
    const float* __restrict__ conv_w, const float* __restrict__ conv_b,
    const float* __restrict__ dt_bias, const float* __restrict__ A_log)
{
  int r = blockIdx.x;          // b*L + l
  int dir = blockIdx.y;
  int l = r & (L_SEQ - 1);
  int t = threadIdx.x;
  const float* zx = ZX + (size_t)dir * ROWS * DINPROJ;
  const float* cw = conv_w + (size_t)dir * CONVDIM * 4;
  const float* cb = conv_b + (size_t)dir * CONVDIM;
  float* xo = XBCC + ((size_t)dir * ROWS + r) * CONVDIM;

  for (int c = t; c < CONVDIM; c += 256) {
    float4 wv4 = *(const float4*)&cw[c * 4];
    const float* wv = (const float*)&wv4;
    float acc = cb[c];
#pragma unroll
    for (int k = 0; k < 4; k++) {
      int ls = l + k - 3;
      if (ls >= 0) acc += zx[(size_t)(r + k - 3) * DINPROJ + DINNER + c] * wv[k];
    }
    xo[c] = silu_f(acc);
  }
  if (t < NHEADS) {
    int h = t;
    float raw = zx[(size_t)r * DINPROJ + DINNER + CONVDIM + h] + dt_bias[dir * NHEADS + h];
    float dt = (raw > 20.0f) ? raw : log1pf(expf(raw));
    float A = -expf(A_log[dir * NHEADS + h]);
    size_t idx = ((size_t)dir * ROWS + r) * NHEADS + h;
    DT[idx] = dt;
    DA[idx] = expf(dt * A);
  }
}

// ---------------- chunked SSM scan, pass 1: local scans ----------------
__global__ __launch_bounds__(64) void scan1_kernel(
    const float* __restrict__ XBCC, const float* __restrict__ DT,
    const float* __restrict__ DA, float* __restrict__ YSSM,
    float* __restrict__ HEND, float* __restrict__ APROD)
{
  int bid = blockIdx.x;
  int g = bid >> 4, c = bid & 15;
  int dir = g >> 5, rem = g & 31;
  int b = rem >> 4, h = rem & 15;
  int lane = threadIdx.x;
  size_t rowbase = (size_t)dir * ROWS + b * L_SEQ + c * CHUNK;
  const float* xb = XBCC + rowbase * CONVDIM;

  float dtv = DT[(rowbase + lane) * NHEADS + h];
  float dav = DA[(rowbase + lane) * NHEADS + h];

  float ap = dav;
#pragma unroll
  for (int off = 1; off < 64; off <<= 1) {
    float o = __shfl_up(ap, off, 64);
    if (lane >= off) ap *= o;
  }
  APROD[((size_t)g * NCHUNK + c) * 64 + lane] = ap;

  __shared__ float BCs[CHUNK][36];
#pragma unroll
  for (int i = 0; i < 8; i++) {
    int l = i * 8 + (lane >> 3), f = lane & 7;
    float4 v = *(const float4*)&xb[(size_t)l * CONVDIM + DINNER + f * 4];
    *(float4*)&BCs[l][f * 4] = v;
  }
  __syncthreads();

  float hs[16];
#pragma unroll
  for (int n = 0; n < 16; n++) hs[n] = 0.0f;

  const float* xp = xb + h * HEADDIM + lane;
  float* yp = YSSM + rowbase * DINNER + h * HEADDIM + lane;

  for (int l = 0; l < CHUNK; l++) {
    float dt = __shfl(dtv, l, 64);
    float da = __shfl(dav, l, 64);
    float xv = xp[(size_t)l * CONVDIM];
    float4 bq[4], cq[4];
#pragma unroll
    for (int q = 0; q < 4; q++) {
      bq[q] = *(const float4*)&BCs[l][q * 4];
      cq[q] = *(const float4*)&BCs[l][16 + q * 4];
    }
    const float* Bv = (const float*)bq;
    const float* Cv = (const float*)cq;
    float dtx = dt * xv;
    float acc = 0.0f;
#pragma unroll
    for (int n = 0; n < 16; n++) {
      hs[n] = hs[n] * da + dtx * Bv[n];
      acc += hs[n] * Cv[n];
    }
    yp[(size_t)l * DINNER] = acc;
  }

  float* he = HEND + ((size_t)g * NCHUNK + c) * 16 * 64;
#pragma unroll
  for (int n = 0; n < 16; n++) he[n * 64 + lane] = hs[n];
}

// ---------------- chunked SSM scan, pass 2: cross-chunk correction --------
__global__ __launch_bounds__(64) void scan2_kernel(
    const float* __restrict__ XBCC, float* __restrict__ YSSM,
    const float* __restrict__ HEND, const float* __restrict__ APROD)
{
  int bid = blockIdx.x;
  int g = bid >> 4, c = bid & 15;
  if (c == 0) return;
  int dir = g >> 5, rem = g & 31;
  int b = rem >> 4, h = rem & 15;
  int lane = threadIdx.x;

  float hstart[16];
#pragma unroll
  for (int n = 0; n < 16; n++) hstart[n] = 0.0f;
  float w = 1.0f;
  for (int j = c - 1; j >= 0; j--) {
    const float* he = HEND + ((size_t)g * NCHUNK + j) * 16 * 64;
#pragma unroll
    for (int n = 0; n < 16; n++) hstart[n] += w * he[n * 64 + lane];
    w *= APROD[((size_t)g * NCHUNK + j) * 64 + 63];
  }

  size_t rowbase = (size_t)dir * ROWS + b * L_SEQ + c * CHUNK;
  const float* xb = XBCC + rowbase * CONVDIM;
  float* yp = YSSM + rowbase * DINNER + h * HEADDIM + lane;
  float apv = APROD[((size_t)g * NCHUNK + c) * 64 + lane];

  __shared__ float Cs[CHUNK][20];
#pragma unroll
  for (int i = 0; i < 4; i++) {
    int l = i * 16 + (lane >> 2), f = lane & 3;
    float4 v = *(const float4*)&xb[(size_t)l * CONVDIM + DINNER + 16 + f * 4];
    *(float4*)&Cs[l][f * 4] = v;
  }
  __syncthreads();

  for (int l = 0; l < CHUNK; l++) {
    float a = __shfl(apv, l, 64);
    float4 cq[4];
#pragma unroll
    for (int q = 0; q < 4; q++) cq[q] = *(const float4*)&Cs[l][q * 4];
    const float* Cv = (const float*)cq;
    float acc = 0.0f;
#pragma unroll
    for (int n = 0; n < 16; n++) acc += Cv[n] * hstart[n];
    yp[(size_t)l * DINNER] += a * acc;
  }
}

// ------- gate (D*xh, silu(z)) + RMS(1024, eps 1e-5), bf16 out -------
__global__ __launch_bounds__(256) void gatenorm_kernel(
    const float* __restrict__ YSSM, const float* __restrict__ XBCC,
    const float* __restrict__ ZX, const float* __restrict__ Dparam,
    const float* __restrict__ mnorm_w, bf16* __restrict__ YB)
{
  int r = blockIdx.x, dir = blockIdx.y, t = threadIdx.x;
  const float* y = YSSM + ((size_t)dir * ROWS + r) * DINNER;
  const float* xb = XBCC + ((size_t)dir * ROWS + r) * CONVDIM;
  const float* z  = ZX   + ((size_t)dir * ROWS + r) * DINPROJ;
  int c = t * 4;
  int h = c >> 6;
  float Dv = Dparam[dir * NHEADS + h];
  float4 yv = *(const float4*)&y[c];
  float4 xv = *(const float4*)&xb[c];
  float4 zv = *(const float4*)&z[c];
  float4 val;
  val.x = (yv.x + Dv*xv.x) * silu_f(zv.x);
  val.y = (yv.y + Dv*xv.y) * silu_f(zv.y);
  val.z = (yv.z + Dv*xv.z) * silu_f(zv.z);
  val.w = (yv.w + Dv*xv.w) * silu_f(zv.w);
  float ss = val.x*val.x + val.y*val.y + val.z*val.z + val.w*val.w;
  ss = wave_sum(ss);
  __shared__ float red[4];
  if ((t & 63) == 0) red[t >> 6] = ss;
  __syncthreads();
  float total = red[0] + red[1] + red[2] + red[3];
  float rs = 1.0f / sqrtf(total * (1.0f / DINNER) + 1e-5f);
  float4 wv = *(const float4*)&mnorm_w[dir * DINNER + c];
  val.x *= rs * wv.x; val.y *= rs * wv.y; val.z *= rs * wv.z; val.w *= rs * wv.w;
  bf16 o4[4] = {(bf16)val.x, (bf16)val.y, (bf16)val.z, (bf16)val.w};
  *(uint2*)&YB[((size_t)dir * ROWS + r) * DINNER + c] = *(uint2*)o4;
}

// ---------------- combine: x += 0.5*(fwd + flip(bwd))*mask ----------------
__global__ __launch_bounds__(128) void combine_kernel(
    float* __restrict__ X, const float* __restrict__ DOUT2,
    const float* __restrict__ mask)
{
  int r = blockIdx.x, t = threadIdx.x;
  int b = r >> 10, l = r & 1023;
  int c = t * 4;
  float m = 0.5f * mask[r];
  float4 f = *(const float4*)&DOUT2[(size_t)r * DMODEL + c];
  size_t br = (size_t)ROWS * DMODEL + ((size_t)(b * L_SEQ + (L_SEQ - 1 - l))) * DMODEL + c;
  float4 bw = *(const float4*)&DOUT2[br];
  float4 x = *(float4*)&X[(size_t)r * DMODEL + c];
  x.x += m * (f.x + bw.x);
  x.y += m * (f.y + bw.y);
  x.z += m * (f.z + bw.z);
  x.w += m * (f.w + bw.w);
  *(float4*)&X[(size_t)r * DMODEL + c] = x;
}

// ---------------- host ----------------
extern "C" void kernel_launch(void* const* d_in, const int* in_sizes, int n_in,
                              void* d_out, int out_size, void* d_ws, size_t ws_size,
                              hipStream_t stream)
{
  const float* in_x    = (const float*)d_in[0];
  const float* in_pe   = (const float*)d_in[1];
  const float* in_mask = (const float*)d_in[2];
  const float* W_in    = (const float*)d_in[3];
  const float* conv_w  = (const float*)d_in[4];
  const float* conv_b  = (const float*)d_in[5];
  const float* A_log   = (const float*)d_in[6];
  const float* Dparam  = (const float*)d_in[7];
  const float* dt_bias = (const float*)d_in[8];
  const float* mnorm_w = (const float*)d_in[9];
  const float* W_out   = (const float*)d_in[10];
  const float* nssm_w  = (const float*)d_in[11];
  const float* ffn_w1  = (const float*)d_in[12];
  const float* ffn_b1  = (const float*)d_in[13];
  const float* ffn_w2  = (const float*)d_in[14];
  const float* ffn_b2  = (const float*)d_in[15];
  const float* nffn_w  = (const float*)d_in[16];
  const float* final_w = (const float*)d_in[17];

  if (ws_size < 110985216) return;

  char* ws = (char*)d_ws;
  float* XBUF  = (float*)(ws + 0);           //  4,194,304  x state f32
  bf16*  SBUF  = (bf16*) (ws + 4194304);     //  2,097,152  rms out bf16
  float* ZX    = (float*)(ws + 6291456);     // 34,340,864  in_proj out f32
  float* XBCC  = (float*)(ws + 40632320);    // 17,301,504  conv+silu out
  float* DTb   = (float*)(ws + 57933824);    //    262,144
  float* DAb   = (float*)(ws + 58195968);    //    262,144
  float* YSSM  = (float*)(ws + 58458112);    // 16,777,216  scan out f32
  bf16*  YB    = (bf16*) (ws + 75235328);    //  8,388,608  gated/normed bf16
  float* DOUT2 = (float*)(ws + 83623936);    //  8,388,608  out_proj / FFN2 partials
  bf16*  MID   = (bf16*) (ws + 92012544);    //  8,388,608  ffn mid bf16
  bf16*  WTIN  = (bf16*) (ws + 100401152);   //  4,292,608
  bf16*  WTOUT = (bf16*) (ws + 104693760);   //  2,097,152
  bf16*  WT1   = (bf16*) (ws + 106790912);   //  2,097,152
  bf16*  WT2   = (bf16*) (ws + 108888064);   //  2,097,152  end 110,985,216

  // scan scratch aliases MID (dead during scan phase)
  float* HEND  = (float*)(ws + 92012544);    //  4,194,304
  float* APROD = (float*)(ws + 96206848);    //    262,144

  hipMemcpyAsync(XBUF, in_x, (size_t)ROWS * DMODEL * sizeof(float),
                 hipMemcpyDeviceToDevice, stream);

  for (int layer = 0; layer < 6; layer++) {
    transpose_cvt<<<dim3(16, 66, 2), 256, 0, stream>>>(
        W_in + (size_t)layer * 2 * DMODEL * DINPROJ, WTIN, DMODEL, DINPROJ);
    transpose_cvt<<<dim3(32, 16, 2), 256, 0, stream>>>(
        W_out + (size_t)layer * 2 * DINNER * DMODEL, WTOUT, DINNER, DMODEL);
    transpose_cvt<<<dim3(16, 64, 1), 256, 0, stream>>>(
        ffn_w1 + (size_t)layer * DMODEL * FFN_DIM, WT1, DMODEL, FFN_DIM);
    transpose_cvt<<<dim3(64, 16, 1), 256, 0, stream>>>(
        ffn_w2 + (size_t)layer * FFN_DIM * DMODEL, WT2, FFN_DIM, DMODEL);

    rms_kernel<<<ROWS, 128, 0, stream>>>(XBUF, nssm_w + layer * DMODEL,
                                         in_pe, in_mask, nullptr, SBUF, 1e-6f);
    // in_proj, both dirs (z=1 reads A rows flipped: r^1023)
    gemm_tile<128, 128, 4, 4, 0><<<dim3(16, 17, 2), 256, 0, stream>>>(
        SBUF, WTIN, ZX, nullptr, ROWS, DINPROJ, DMODEL, DMODEL, DMODEL,
        0L, (long)DINPROJ * DMODEL, (long)ROWS * DINPROJ, 1, nullptr);
    convdt_kernel<<<dim3(ROWS, 2), 256, 0, stream>>>(
        ZX, XBCC, DTb, DAb,
        conv_w + (size_t)layer * 2 * CONVDIM * 4, conv_b + (size_t)layer * 2 * CONVDIM,
        dt_bias + layer * 2 * NHEADS, A_log + layer * 2 * NHEADS);
    scan1_kernel<<<1024, 64, 0, stream>>>(XBCC, DTb, DAb, YSSM, HEND, APROD);
    scan2_kernel<<<1024, 64, 0, stream>>>(XBCC, YSSM, HEND, APROD);
    gatenorm_kernel<<<dim3(ROWS, 2), 256, 0, stream>>>(
        YSSM, XBCC, ZX, Dparam + layer * 2 * NHEADS, mnorm_w + layer * 2 * DINNER, YB);
    gemm_tile<128, 64, 4, 2, 0><<<dim3(16, 8, 2), 256, 0, stream>>>(
        YB, WTOUT, DOUT2, nullptr, ROWS, DMODEL, DINNER, DINNER, DINNER,
        (long)ROWS * DINNER, (long)DMODEL * DINNER, (long)ROWS * DMODEL, 0, nullptr);
    combine_kernel<<<ROWS, 128, 0, stream>>>(XBUF, DOUT2, in_mask);

    // FFN
    rms_kernel<<<ROWS, 128, 0, stream>>>(XBUF, nffn_w + layer * DMODEL,
                                         nullptr, nullptr, nullptr, SBUF, 1e-6f);
    gemm_tile<128, 128, 4, 4, 1><<<dim3(16, 16, 1), 256, 0, stream>>>(
        SBUF, WT1, nullptr, MID, ROWS, FFN_DIM, DMODEL, DMODEL, DMODEL,
        0L, 0L, 0L, 0, ffn_b1 + layer * FFN_DIM);
    // FFN2 split-K=2: z shifts k-start by 1024 in both A and B; partials in DOUT2
    gemm_tile<128, 64, 4, 2, 0><<<dim3(16, 8, 2), 256, 0, stream>>>(
        MID, WT2, DOUT2, nullptr, ROWS, DMODEL, 1024, FFN_DIM, FFN_DIM,
        1024L, 1024L, (long)ROWS * DMODEL, 0, nullptr);
    ffn2_reduce<<<ROWS, 128, 0, stream>>>(XBUF, DOUT2, ffn_b2 + layer * DMODEL);
  }
  rms_kernel<<<ROWS, 128, 0, stream>>>(XBUF, final_w, nullptr, nullptr,
                                       (float*)d_out, nullptr, 1e-6f);
}

// Round 6
// 1185.417 us; speedup vs baseline: 3.2555x; 1.1174x over previous
//
#include <hip/hip_runtime.h>
#include <cstdint>
#include <cstddef>

typedef __bf16 bf16;
typedef __bf16 bf16x4 __attribute__((ext_vector_type(4)));
typedef __bf16 bf16x8 __attribute__((ext_vector_type(8)));
typedef float f32x4 __attribute__((ext_vector_type(4)));

#define L_SEQ   1024
#define DMODEL  512
#define DINNER  1024
#define DSTATE  16
#define NHEADS  16
#define HEADDIM 64
#define CONVDIM 1056
#define DINPROJ 2096
#define FFN_DIM 2048
#define ROWS    2048   // B*L
#define CHUNK   64
#define NCHUNK  16

__device__ __forceinline__ float wave_sum(float v) {
#pragma unroll
  for (int off = 32; off; off >>= 1) v += __shfl_down(v, off, 64);
  return v;
}
__device__ __forceinline__ float silu_f(float x) { return x / (1.0f + expf(-x)); }

// ---------------- RMS norm (+pe/mask), bf16 out (used once, layer 0) -------
__global__ __launch_bounds__(128) void rms_kernel(
    const float* __restrict__ x, const float* __restrict__ w,
    const float* __restrict__ pe, const float* __restrict__ mask,
    bf16* __restrict__ outb)
{
  int r = blockIdx.x, t = threadIdx.x;
  float4 v = ((const float4*)(x + (size_t)r * DMODEL))[t];
  float ss = v.x*v.x + v.y*v.y + v.z*v.z + v.w*v.w;
  ss = wave_sum(ss);
  __shared__ float red[2];
  if ((t & 63) == 0) red[t >> 6] = ss;
  __syncthreads();
  float rs = 1.0f / sqrtf((red[0] + red[1]) * (1.0f / DMODEL) + 1e-6f);
  float4 wv = ((const float4*)w)[t];
  float4 p = ((const float4*)(pe + (size_t)r * DMODEL))[t];
  float m = mask[r];
  bf16x4 o;
  o[0] = (bf16)((v.x*rs*wv.x + p.x) * m);
  o[1] = (bf16)((v.y*rs*wv.y + p.y) * m);
  o[2] = (bf16)((v.z*rs*wv.z + p.z) * m);
  o[3] = (bf16)((v.w*rs*wv.w + p.w) * m);
  *(bf16x4*)&outb[(size_t)r * DMODEL + t * 4] = o;
}

// ------- ONE dispatch: transpose+cvt ALL weights of ALL layers -------------
__global__ __launch_bounds__(256) void transpose_all(
    const float* __restrict__ W_in, const float* __restrict__ W_out,
    const float* __restrict__ f1, const float* __restrict__ f2,
    bf16* __restrict__ TIN, bf16* __restrict__ TOUT,
    bf16* __restrict__ T1, bf16* __restrict__ T2)
{
  int bid = blockIdx.x;
  const float* src; bf16* dst; int K, N, k0, n0;
  if (bid < 12672) {                 // W_in: 12 slices x (16 x 66) tiles
    int slice = bid / 1056, rem = bid % 1056;
    K = 512; N = 2096;
    k0 = (rem % 16) * 32; n0 = (rem / 16) * 32;
    src = W_in + (size_t)slice * K * N;  dst = TIN + (size_t)slice * N * K;
  } else if (bid < 18816) {          // W_out: 12 x (32 x 16)
    int t2 = bid - 12672;
    int slice = t2 / 512, rem = t2 % 512;
    K = 1024; N = 512;
    k0 = (rem % 32) * 32; n0 = (rem / 32) * 32;
    src = W_out + (size_t)slice * K * N; dst = TOUT + (size_t)slice * N * K;
  } else if (bid < 24960) {          // ffn1: 6 x (16 x 64)
    int t3 = bid - 18816;
    int slice = t3 / 1024, rem = t3 % 1024;
    K = 512; N = 2048;
    k0 = (rem % 16) * 32; n0 = (rem / 16) * 32;
    src = f1 + (size_t)slice * K * N;    dst = T1 + (size_t)slice * N * K;
  } else {                           // ffn2: 6 x (64 x 16)
    int t4 = bid - 24960;
    int slice = t4 / 1024, rem = t4 % 1024;
    K = 2048; N = 512;
    k0 = (rem % 64) * 32; n0 = (rem / 64) * 32;
    src = f2 + (size_t)slice * K * N;    dst = T2 + (size_t)slice * N * K;
  }
  __shared__ float tile[32][33];
  int tx = threadIdx.x & 31, ty = threadIdx.x >> 5;
#pragma unroll
  for (int i = 0; i < 4; i++) {
    int k = k0 + ty + 8*i, n = n0 + tx;
    tile[ty + 8*i][tx] = (k < K && n < N) ? src[(size_t)k * N + n] : 0.0f;
  }
  __syncthreads();
#pragma unroll
  for (int i = 0; i < 4; i++) {
    int n = n0 + ty + 8*i, k = k0 + tx;
    if (n < N && k < K) dst[(size_t)n * K + k] = (bf16)tile[tx][ty + 8*i];
  }
}

// ---------------- bf16 MFMA GEMM, global_load_lds staging -------------------
// MODE 0: f32 out  MODE 1: +bias,gelu,bf16 out  MODE 3: bf16 out + f32 dt tail
template<int BM, int BN, int FI, int FJ, int MODE>
__global__ __launch_bounds__(256) void gemm_tile(
    const bf16* __restrict__ A, const bf16* __restrict__ BT,
    float* __restrict__ Cf, bf16* __restrict__ Cb,
    int M, int N, int K, int lda, int ldb,
    long aOffz, long bOffz, long cOffz, int flipz,
    const float* __restrict__ bias)
{
  constexpr int TG = (BM + BN) * 4;
  constexpr int NI = TG / 256;

  int z = blockIdx.z;
  A  += (size_t)z * aOffz;
  BT += (size_t)z * bOffz;
  long coff = (size_t)z * cOffz;
  int doflip = (flipz && z == 1);

  __shared__ __align__(16) bf16 Tile[(BM + BN) * 32];
  bf16* As = Tile;
  bf16* Bs = Tile + BM * 32;

  int m0 = blockIdx.x * BM, n0 = blockIdx.y * BN;
  int t = threadIdx.x;
  int lane = t & 63, w = t >> 6;
  int wr = w >> 1, wc = w & 1;
  int lr = lane & 15, lq = lane >> 4;

  const bf16* gsrc[NI];
#pragma unroll
  for (int i = 0; i < NI; i++) {
    int g = w * (TG / 4) + i * 64 + lane;
    if (g < BM * 4) {
      int row = g >> 2, kp = g & 3;
      int gr = m0 + row;
      if (doflip) gr ^= (L_SEQ - 1);
      gsrc[i] = A + (size_t)gr * lda + kp * 8;
    } else {
      int g2 = g - BM * 4;
      int row = g2 >> 2, kp = g2 & 3;
      int gn = n0 + row; if (gn >= N) gn = N - 1;
      gsrc[i] = BT + (size_t)gn * ldb + kp * 8;
    }
  }

  f32x4 zf = {0.0f, 0.0f, 0.0f, 0.0f};
  f32x4 acc[FI][FJ];
#pragma unroll
  for (int i = 0; i < FI; i++)
#pragma unroll
    for (int j = 0; j < FJ; j++) acc[i][j] = zf;

  for (int k0 = 0; k0 < K; k0 += 32) {
#pragma unroll
    for (int i = 0; i < NI; i++) {
      int chunk = w * (TG / 4) + i * 64;
      __builtin_amdgcn_global_load_lds(
          (const __attribute__((address_space(1))) void*)(gsrc[i] + k0),
          (__attribute__((address_space(3))) void*)&Tile[chunk * 8],
          16, 0, 0);
    }
    __syncthreads();

    bf16x8 af[FI], bfv[FJ];
#pragma unroll
    for (int i = 0; i < FI; i++)
      af[i] = *(const bf16x8*)&As[(wr * 64 + i * 16 + lr) * 32 + lq * 8];
#pragma unroll
    for (int j = 0; j < FJ; j++)
      bfv[j] = *(const bf16x8*)&Bs[(wc * (BN / 2) + j * 16 + lr) * 32 + lq * 8];
#pragma unroll
    for (int i = 0; i < FI; i++)
#pragma unroll
      for (int j = 0; j < FJ; j++)
        acc[i][j] = __builtin_amdgcn_mfma_f32_16x16x32_bf16(af[i], bfv[j], acc[i][j], 0, 0, 0);
    __syncthreads();
  }

#pragma unroll
  for (int i = 0; i < FI; i++) {
    int growb = m0 + wr * 64 + i * 16 + lq * 4;
#pragma unroll
    for (int j = 0; j < FJ; j++) {
      int gcol = n0 + wc * (BN / 2) + j * 16 + lr;
      if (gcol >= N) continue;
#pragma unroll
      for (int rr = 0; rr < 4; rr++) {
        int grow = growb + rr;
        float v = acc[i][j][rr];
        if (MODE == 1) {
          v += bias[gcol];
          v = 0.5f * v * (1.0f + erff(v * 0.70710678118f));
          Cb[coff + (size_t)grow * N + gcol] = (bf16)v;
        } else if (MODE == 3) {
          Cb[coff + (size_t)grow * N + gcol] = (bf16)v;
          if (gcol >= DINNER + CONVDIM)
            Cf[(size_t)z * ROWS * 16 + (size_t)grow * 16 + (gcol - (DINNER + CONVDIM))] = v;
        } else {
          Cf[coff + (size_t)grow * N + gcol] = v;
        }
      }
    }
  }
}

// -------- conv(4-tap causal)+silu (bf16 in/out), plus dt/dA from raw -------
__global__ __launch_bounds__(256) void convdt_kernel(
    const bf16* __restrict__ ZX, const float* __restrict__ DTRAW,
    bf16* __restrict__ XBCC, float* __restrict__ DT, float* __restrict__ DA,
    const float* __restrict__ conv_w, const float* __restrict__ conv_b,
    const float* __restrict__ dt_bias, const float* __restrict__ A_log)
{
  int r = blockIdx.x, dir = blockIdx.y;
  int l = r & (L_SEQ - 1);
  int t = threadIdx.x;
  const bf16* zx = ZX + (size_t)dir * ROWS * DINPROJ;
  const float* cw = conv_w + (size_t)dir * CONVDIM * 4;
  const float* cb = conv_b + (size_t)dir * CONVDIM;
  bf16* xo = XBCC + ((size_t)dir * ROWS + r) * CONVDIM;

  for (int ci = t; ci < CONVDIM / 4; ci += 256) {
    int c = ci * 4;
    f32x4 wch[4];
#pragma unroll
    for (int j = 0; j < 4; j++) wch[j] = *(const f32x4*)&cw[(c + j) * 4];
    f32x4 cbv = *(const f32x4*)&cb[c];
    float acc[4] = {cbv[0], cbv[1], cbv[2], cbv[3]};
#pragma unroll
    for (int k = 0; k < 4; k++) {
      int ls = l + k - 3;
      if (ls < 0) continue;
      bf16x4 iv = *(const bf16x4*)&zx[(size_t)(r + k - 3) * DINPROJ + DINNER + c];
#pragma unroll
      for (int j = 0; j < 4; j++) acc[j] += (float)iv[j] * wch[j][k];
    }
    bf16x4 o;
#pragma unroll
    for (int j = 0; j < 4; j++) o[j] = (bf16)silu_f(acc[j]);
    *(bf16x4*)&xo[c] = o;
  }
  if (t < NHEADS) {
    int h = t;
    float raw = DTRAW[((size_t)dir * ROWS + r) * 16 + h] + dt_bias[dir * NHEADS + h];
    float dt = (raw > 20.0f) ? raw : log1pf(expf(raw));
    float A = -expf(A_log[dir * NHEADS + h]);
    size_t idx = ((size_t)dir * ROWS + r) * NHEADS + h;
    DT[idx] = dt;
    DA[idx] = expf(dt * A);
  }
}

// ---------------- chunked SSM scan, pass 1: local scans ----------------
__global__ __launch_bounds__(64) void scan1_kernel(
    const bf16* __restrict__ XBCC, const float* __restrict__ DT,
    const float* __restrict__ DA, float* __restrict__ YSSM,
    float* __restrict__ HEND, float* __restrict__ APROD)
{
  int bid = blockIdx.x;
  int g = bid >> 4, c = bid & 15;
  int dir = g >> 5, rem = g & 31;
  int b = rem >> 4, h = rem & 15;
  int lane = threadIdx.x;
  size_t rowbase = (size_t)dir * ROWS + b * L_SEQ + c * CHUNK;
  const bf16* xb = XBCC + rowbase * CONVDIM;

  float dtv = DT[(rowbase + lane) * NHEADS + h];
  float dav = DA[(rowbase + lane) * NHEADS + h];

  float ap = dav;
#pragma unroll
  for (int off = 1; off < 64; off <<= 1) {
    float o = __shfl_up(ap, off, 64);
    if (lane >= off) ap *= o;
  }
  APROD[((size_t)g * NCHUNK + c) * 64 + lane] = ap;

  __shared__ float BCs[CHUNK][36];
#pragma unroll
  for (int i = 0; i < 8; i++) {
    int l = i * 8 + (lane >> 3), f = lane & 7;
    bf16x4 v = *(const bf16x4*)&xb[(size_t)l * CONVDIM + DINNER + f * 4];
#pragma unroll
    for (int q = 0; q < 4; q++) BCs[l][f * 4 + q] = (float)v[q];
  }
  __syncthreads();

  float hs[16];
#pragma unroll
  for (int n = 0; n < 16; n++) hs[n] = 0.0f;

  const bf16* xp = xb + h * HEADDIM + lane;
  float* yp = YSSM + rowbase * DINNER + h * HEADDIM + lane;

  for (int l = 0; l < CHUNK; l++) {
    float dt = __shfl(dtv, l, 64);
    float da = __shfl(dav, l, 64);
    float xv = (float)xp[(size_t)l * CONVDIM];
    float4 bq[4], cq[4];
#pragma unroll
    for (int q = 0; q < 4; q++) {
      bq[q] = *(const float4*)&BCs[l][q * 4];
      cq[q] = *(const float4*)&BCs[l][16 + q * 4];
    }
    const float* Bv = (const float*)bq;
    const float* Cv = (const float*)cq;
    float dtx = dt * xv;
    float acc = 0.0f;
#pragma unroll
    for (int n = 0; n < 16; n++) {
      hs[n] = hs[n] * da + dtx * Bv[n];
      acc += hs[n] * Cv[n];
    }
    yp[(size_t)l * DINNER] = acc;
  }

  float* he = HEND + ((size_t)g * NCHUNK + c) * 16 * 64;
#pragma unroll
  for (int n = 0; n < 16; n++) he[n * 64 + lane] = hs[n];
}

// ---------------- chunked SSM scan, pass 2: cross-chunk correction --------
__global__ __launch_bounds__(64) void scan2_kernel(
    const bf16* __restrict__ XBCC, float* __restrict__ YSSM,
    const float* __restrict__ HEND, const float* __restrict__ APROD)
{
  int bid = blockIdx.x;
  int g = bid >> 4, c = bid & 15;
  if (c == 0) return;
  int dir = g >> 5, rem = g & 31;
  int b = rem >> 4, h = rem & 15;
  int lane = threadIdx.x;

  float hstart[16];
#pragma unroll
  for (int n = 0; n < 16; n++) hstart[n] = 0.0f;
  float w = 1.0f;
  for (int j = c - 1; j >= 0; j--) {
    const float* he = HEND + ((size_t)g * NCHUNK + j) * 16 * 64;
#pragma unroll
    for (int n = 0; n < 16; n++) hstart[n] += w * he[n * 64 + lane];
    w *= APROD[((size_t)g * NCHUNK + j) * 64 + 63];
  }

  size_t rowbase = (size_t)dir * ROWS + b * L_SEQ + c * CHUNK;
  const bf16* xb = XBCC + rowbase * CONVDIM;
  float* yp = YSSM + rowbase * DINNER + h * HEADDIM + lane;
  float apv = APROD[((size_t)g * NCHUNK + c) * 64 + lane];

  __shared__ float Cs[CHUNK][20];
#pragma unroll
  for (int i = 0; i < 4; i++) {
    int l = i * 16 + (lane >> 2), f = lane & 3;
    bf16x4 v = *(const bf16x4*)&xb[(size_t)l * CONVDIM + DINNER + 16 + f * 4];
#pragma unroll
    for (int q = 0; q < 4; q++) Cs[l][f * 4 + q] = (float)v[q];
  }
  __syncthreads();

  for (int l = 0; l < CHUNK; l++) {
    float a = __shfl(apv, l, 64);
    float4 cq[4];
#pragma unroll
    for (int q = 0; q < 4; q++) cq[q] = *(const float4*)&Cs[l][q * 4];
    const float* Cv = (const float*)cq;
    float acc = 0.0f;
#pragma unroll
    for (int n = 0; n < 16; n++) acc += Cv[n] * hstart[n];
    yp[(size_t)l * DINNER] += a * acc;
  }
}

// ------- gate (D*xh, silu(z)) + RMS(1024, eps 1e-5), bf16 out -------
__global__ __launch_bounds__(256) void gatenorm_kernel(
    const float* __restrict__ YSSM, const bf16* __restrict__ XBCC,
    const bf16* __restrict__ ZX, const float* __restrict__ Dparam,
    const float* __restrict__ mnorm_w, bf16* __restrict__ YB)
{
  int r = blockIdx.x, dir = blockIdx.y, t = threadIdx.x;
  const float* y = YSSM + ((size_t)dir * ROWS + r) * DINNER;
  const bf16* xb = XBCC + ((size_t)dir * ROWS + r) * CONVDIM;
  const bf16* z  = ZX   + ((size_t)dir * ROWS + r) * DINPROJ;
  int c = t * 4;
  int h = c >> 6;
  float Dv = Dparam[dir * NHEADS + h];
  float4 yv = *(const float4*)&y[c];
  bf16x4 xv4 = *(const bf16x4*)&xb[c];
  bf16x4 zv4 = *(const bf16x4*)&z[c];
  float val[4];
  val[0] = (yv.x + Dv*(float)xv4[0]) * silu_f((float)zv4[0]);
  val[1] = (yv.y + Dv*(float)xv4[1]) * silu_f((float)zv4[1]);
  val[2] = (yv.z + Dv*(float)xv4[2]) * silu_f((float)zv4[2]);
  val[3] = (yv.w + Dv*(float)xv4[3]) * silu_f((float)zv4[3]);
  float ss = val[0]*val[0] + val[1]*val[1] + val[2]*val[2] + val[3]*val[3];
  ss = wave_sum(ss);
  __shared__ float red[4];
  if ((t & 63) == 0) red[t >> 6] = ss;
  __syncthreads();
  float total = red[0] + red[1] + red[2] + red[3];
  float rs = 1.0f / sqrtf(total * (1.0f / DINNER) + 1e-5f);
  float4 wv = *(const float4*)&mnorm_w[dir * DINNER + c];
  bf16x4 o;
  o[0] = (bf16)(val[0] * rs * wv.x);
  o[1] = (bf16)(val[1] * rs * wv.y);
  o[2] = (bf16)(val[2] * rs * wv.z);
  o[3] = (bf16)(val[3] * rs * wv.w);
  *(bf16x4*)&YB[((size_t)dir * ROWS + r) * DINNER + c] = o;
}

// ------ combine (x += 0.5*(f+flip(b))*mask) + FFN RMS, bf16 out ------
__global__ __launch_bounds__(128) void combine_rms(
    const float* __restrict__ Xsrc, float* __restrict__ X,
    const float* __restrict__ P, const float* __restrict__ mask,
    const float* __restrict__ w, bf16* __restrict__ outb)
{
  int r = blockIdx.x, t = threadIdx.x;
  int b = r >> 10, l = r & 1023;
  int c = t * 4;
  float m = 0.5f * mask[r];
  float4 f = *(const float4*)&P[(size_t)r * DMODEL + c];
  size_t br = (size_t)ROWS * DMODEL + ((size_t)(b * L_SEQ + (L_SEQ - 1 - l))) * DMODEL + c;
  float4 bw = *(const float4*)&P[br];
  float4 x = *(const float4*)&Xsrc[(size_t)r * DMODEL + c];
  x.x += m * (f.x + bw.x);
  x.y += m * (f.y + bw.y);
  x.z += m * (f.z + bw.z);
  x.w += m * (f.w + bw.w);
  *(float4*)&X[(size_t)r * DMODEL + c] = x;
  float ss = x.x*x.x + x.y*x.y + x.z*x.z + x.w*x.w;
  ss = wave_sum(ss);
  __shared__ float red[2];
  if ((t & 63) == 0) red[t >> 6] = ss;
  __syncthreads();
  float rs = 1.0f / sqrtf((red[0] + red[1]) * (1.0f / DMODEL) + 1e-6f);
  float4 wv = *(const float4*)&w[c];
  bf16x4 o;
  o[0] = (bf16)(x.x * rs * wv.x);
  o[1] = (bf16)(x.y * rs * wv.y);
  o[2] = (bf16)(x.z * rs * wv.z);
  o[3] = (bf16)(x.w * rs * wv.w);
  *(bf16x4*)&outb[(size_t)r * DMODEL + c] = o;
}

// ------ FFN2 splitK reduce + bias + resid, then RMS (next-layer or final) ---
__global__ __launch_bounds__(128) void reduce_rms(
    float* __restrict__ X, const float* __restrict__ P,
    const float* __restrict__ bias, const float* __restrict__ w,
    const float* __restrict__ pe, const float* __restrict__ mask,
    bf16* __restrict__ outb, float* __restrict__ outf)
{
  int r = blockIdx.x, t = threadIdx.x;
  int c = t * 4;
  float4 a  = *(const float4*)&P[(size_t)r * DMODEL + c];
  float4 b2 = *(const float4*)&P[(size_t)ROWS * DMODEL + (size_t)r * DMODEL + c];
  float4 bi = *(const float4*)&bias[c];
  float4 x  = *(float4*)&X[(size_t)r * DMODEL + c];
  x.x += a.x + b2.x + bi.x;
  x.y += a.y + b2.y + bi.y;
  x.z += a.z + b2.z + bi.z;
  x.w += a.w + b2.w + bi.w;
  *(float4*)&X[(size_t)r * DMODEL + c] = x;
  float ss = x.x*x.x + x.y*x.y + x.z*x.z + x.w*x.w;
  ss = wave_sum(ss);
  __shared__ float red[2];
  if ((t & 63) == 0) red[t >> 6] = ss;
  __syncthreads();
  float rs = 1.0f / sqrtf((red[0] + red[1]) * (1.0f / DMODEL) + 1e-6f);
  float4 wv = *(const float4*)&w[c];
  float4 o;
  o.x = x.x*rs*wv.x; o.y = x.y*rs*wv.y; o.z = x.z*rs*wv.z; o.w = x.w*rs*wv.w;
  if (pe) {
    float4 p = *(const float4*)&pe[(size_t)r * DMODEL + c];
    float m = mask[r];
    o.x = (o.x + p.x)*m; o.y = (o.y + p.y)*m; o.z = (o.z + p.z)*m; o.w = (o.w + p.w)*m;
  }
  if (outb) {
    bf16x4 ob = {(bf16)o.x, (bf16)o.y, (bf16)o.z, (bf16)o.w};
    *(bf16x4*)&outb[(size_t)r * DMODEL + c] = ob;
  } else {
    *(float4*)&outf[(size_t)r * DMODEL + c] = o;
  }
}

// ---------------- host ----------------
extern "C" void kernel_launch(void* const* d_in, const int* in_sizes, int n_in,
                              void* d_out, int out_size, void* d_ws, size_t ws_size,
                              hipStream_t stream)
{
  const float* in_x    = (const float*)d_in[0];
  const float* in_pe   = (const float*)d_in[1];
  const float* in_mask = (const float*)d_in[2];
  const float* W_in    = (const float*)d_in[3];
  const float* conv_w  = (const float*)d_in[4];
  const float* conv_b  = (const float*)d_in[5];
  const float* A_log   = (const float*)d_in[6];
  const float* Dparam  = (const float*)d_in[7];
  const float* dt_bias = (const float*)d_in[8];
  const float* mnorm_w = (const float*)d_in[9];
  const float* W_out   = (const float*)d_in[10];
  const float* nssm_w  = (const float*)d_in[11];
  const float* ffn_w1  = (const float*)d_in[12];
  const float* ffn_b1  = (const float*)d_in[13];
  const float* ffn_w2  = (const float*)d_in[14];
  const float* ffn_b2  = (const float*)d_in[15];
  const float* nffn_w  = (const float*)d_in[16];
  const float* final_w = (const float*)d_in[17];

  if (ws_size < 142802944) return;

  // Corrected layout (R4/R5 bug: WTINa was 65,536 B short -> overflowed into
  // WTOUTa, clobbering layer-0 W_out^T. WTINa true size:
  // 12 * 2096 * 512 * 2 = 25,755,648 bytes.)
  char* ws = (char*)d_ws;
  float* XBUF  = (float*)(ws + 0);            //  4,194,304
  bf16*  SBUF  = (bf16*) (ws + 4194304);      //  2,097,152
  bf16*  ZXb   = (bf16*) (ws + 6291456);      // 17,170,432
  float* DTRAW = (float*)(ws + 23461888);     //    262,144
  bf16*  XBCC  = (bf16*) (ws + 23724032);     //  8,650,752
  float* DTb   = (float*)(ws + 32374784);     //    262,144
  float* DAb   = (float*)(ws + 32636928);     //    262,144
  float* YSSM  = (float*)(ws + 32899072);     // 16,777,216
  bf16*  YB    = (bf16*) (ws + 49676288);     //  8,388,608
  float* DOUT2 = (float*)(ws + 58064896);     //  8,388,608
  bf16*  MID   = (bf16*) (ws + 66453504);     //  8,388,608
  float* HEND  = (float*)(ws + 74842112);     //  4,194,304
  float* APROD = (float*)(ws + 79036416);     //    262,144
  bf16*  WTINa = (bf16*) (ws + 79298560);     // 25,755,648  (FIXED)
  bf16*  WTOUTa= (bf16*) (ws + 105054208);    // 12,582,912
  bf16*  WT1a  = (bf16*) (ws + 117637120);    // 12,582,912
  bf16*  WT2a  = (bf16*) (ws + 130220032);    // 12,582,912  end 142,802,944

  // all-layer weight transpose+cvt in ONE dispatch
  transpose_all<<<31104, 256, 0, stream>>>(W_in, W_out, ffn_w1, ffn_w2,
                                           WTINa, WTOUTa, WT1a, WT2a);
  // layer-0 input norm
  rms_kernel<<<ROWS, 128, 0, stream>>>(in_x, nssm_w, in_pe, in_mask, SBUF);

  for (int layer = 0; layer < 6; layer++) {
    const bf16* WTIN  = WTINa  + (size_t)layer * 2 * DMODEL * DINPROJ;
    const bf16* WTOUT = WTOUTa + (size_t)layer * 2 * DINNER * DMODEL;
    const bf16* WT1   = WT1a   + (size_t)layer * DMODEL * FFN_DIM;
    const bf16* WT2   = WT2a   + (size_t)layer * FFN_DIM * DMODEL;

    // in_proj both dirs (dir1 reads A rows flipped); bf16 out + f32 dt tail
    gemm_tile<128, 128, 4, 4, 3><<<dim3(16, 17, 2), 256, 0, stream>>>(
        SBUF, WTIN, DTRAW, ZXb, ROWS, DINPROJ, DMODEL, DMODEL, DMODEL,
        0L, (long)DINPROJ * DMODEL, (long)ROWS * DINPROJ, 1, nullptr);
    convdt_kernel<<<dim3(ROWS, 2), 256, 0, stream>>>(
        ZXb, DTRAW, XBCC, DTb, DAb,
        conv_w + (size_t)layer * 2 * CONVDIM * 4, conv_b + (size_t)layer * 2 * CONVDIM,
        dt_bias + layer * 2 * NHEADS, A_log + layer * 2 * NHEADS);
    scan1_kernel<<<1024, 64, 0, stream>>>(XBCC, DTb, DAb, YSSM, HEND, APROD);
    scan2_kernel<<<1024, 64, 0, stream>>>(XBCC, YSSM, HEND, APROD);
    gatenorm_kernel<<<dim3(ROWS, 2), 256, 0, stream>>>(
        YSSM, XBCC, ZXb, Dparam + layer * 2 * NHEADS, mnorm_w + layer * 2 * DINNER, YB);
    gemm_tile<128, 64, 4, 2, 0><<<dim3(16, 8, 2), 256, 0, stream>>>(
        YB, WTOUT, DOUT2, nullptr, ROWS, DMODEL, DINNER, DINNER, DINNER,
        (long)ROWS * DINNER, (long)DMODEL * DINNER, (long)ROWS * DMODEL, 0, nullptr);
    combine_rms<<<ROWS, 128, 0, stream>>>(
        layer == 0 ? in_x : XBUF, XBUF, DOUT2, in_mask, nffn_w + layer * DMODEL, SBUF);

    // FFN
    gemm_tile<128, 128, 4, 4, 1><<<dim3(16, 16, 1), 256, 0, stream>>>(
        SBUF, WT1, nullptr, MID, ROWS, FFN_DIM, DMODEL, DMODEL, DMODEL,
        0L, 0L, 0L, 0, ffn_b1 + layer * FFN_DIM);
    gemm_tile<128, 64, 4, 2, 0><<<dim3(16, 8, 2), 256, 0, stream>>>(
        MID, WT2, DOUT2, nullptr, ROWS, DMODEL, 1024, FFN_DIM, FFN_DIM,
        1024L, 1024L, (long)ROWS * DMODEL, 0, nullptr);
    if (layer < 5) {
      reduce_rms<<<ROWS, 128, 0, stream>>>(
          XBUF, DOUT2, ffn_b2 + layer * DMODEL, nssm_w + (layer + 1) * DMODEL,
          in_pe, in_mask, SBUF, nullptr);
    } else {
      reduce_rms<<<ROWS, 128, 0, stream>>>(
          XBUF, DOUT2, ffn_b2 + layer * DMODEL, final_w,
          nullptr, nullptr, nullptr, (float*)d_out);
    }
  }
}

// Round 7
// 1076.961 us; speedup vs baseline: 3.5834x; 1.1007x over previous
//
#include <hip/hip_runtime.h>
#include <cstdint>
#include <cstddef>

typedef __bf16 bf16;
typedef __bf16 bf16x4 __attribute__((ext_vector_type(4)));
typedef __bf16 bf16x8 __attribute__((ext_vector_type(8)));
typedef float f32x4 __attribute__((ext_vector_type(4)));

#define L_SEQ   1024
#define DMODEL  512
#define DINNER  1024
#define DSTATE  16
#define NHEADS  16
#define HEADDIM 64
#define CONVDIM 1056
#define DINPROJ 2096
#define FFN_DIM 2048
#define ROWS    2048   // B*L
#define CHUNK   64
#define NCHUNK  16

__device__ __forceinline__ float wave_sum(float v) {
#pragma unroll
  for (int off = 32; off; off >>= 1) v += __shfl_down(v, off, 64);
  return v;
}
__device__ __forceinline__ float silu_f(float x) { return x / (1.0f + expf(-x)); }

// ---------------- RMS norm (+pe/mask), bf16 out (used once, layer 0) -------
__global__ __launch_bounds__(128) void rms_kernel(
    const float* __restrict__ x, const float* __restrict__ w,
    const float* __restrict__ pe, const float* __restrict__ mask,
    bf16* __restrict__ outb)
{
  int r = blockIdx.x, t = threadIdx.x;
  float4 v = ((const float4*)(x + (size_t)r * DMODEL))[t];
  float ss = v.x*v.x + v.y*v.y + v.z*v.z + v.w*v.w;
  ss = wave_sum(ss);
  __shared__ float red[2];
  if ((t & 63) == 0) red[t >> 6] = ss;
  __syncthreads();
  float rs = 1.0f / sqrtf((red[0] + red[1]) * (1.0f / DMODEL) + 1e-6f);
  float4 wv = ((const float4*)w)[t];
  float4 p = ((const float4*)(pe + (size_t)r * DMODEL))[t];
  float m = mask[r];
  bf16x4 o;
  o[0] = (bf16)((v.x*rs*wv.x + p.x) * m);
  o[1] = (bf16)((v.y*rs*wv.y + p.y) * m);
  o[2] = (bf16)((v.z*rs*wv.z + p.z) * m);
  o[3] = (bf16)((v.w*rs*wv.w + p.w) * m);
  *(bf16x4*)&outb[(size_t)r * DMODEL + t * 4] = o;
}

// ------- transpose+cvt ALL weights, ONE dispatch, full-128B-line writes ----
// tiles: 64(k) x 32(n); write phase emits 128-B (64 bf16) contiguous rows.
__global__ __launch_bounds__(256) void transpose_all(
    const float* __restrict__ W_in, const float* __restrict__ W_out,
    const float* __restrict__ f1, const float* __restrict__ f2,
    bf16* __restrict__ TIN, bf16* __restrict__ TOUT,
    bf16* __restrict__ T1, bf16* __restrict__ T2)
{
  int bid = blockIdx.x;
  const float* src; bf16* dst; int K, N, k0, n0;
  if (bid < 6336) {                  // W_in: 12 x (8 kt x 66 nt)
    int slice = bid / 528, rem = bid % 528;
    K = 512; N = 2096;
    k0 = (rem % 8) * 64; n0 = (rem / 8) * 32;
    src = W_in + (size_t)slice * K * N;  dst = TIN + (size_t)slice * N * K;
  } else if (bid < 9408) {           // W_out: 12 x (16 x 16)
    int t2 = bid - 6336;
    int slice = t2 / 256, rem = t2 % 256;
    K = 1024; N = 512;
    k0 = (rem % 16) * 64; n0 = (rem / 16) * 32;
    src = W_out + (size_t)slice * K * N; dst = TOUT + (size_t)slice * N * K;
  } else if (bid < 12480) {          // ffn1: 6 x (8 x 64)
    int t3 = bid - 9408;
    int slice = t3 / 512, rem = t3 % 512;
    K = 512; N = 2048;
    k0 = (rem % 8) * 64; n0 = (rem / 8) * 32;
    src = f1 + (size_t)slice * K * N;    dst = T1 + (size_t)slice * N * K;
  } else {                           // ffn2: 6 x (32 x 16)
    int t4 = bid - 12480;
    int slice = t4 / 512, rem = t4 % 512;
    K = 2048; N = 512;
    k0 = (rem % 32) * 64; n0 = (rem / 32) * 32;
    src = f2 + (size_t)slice * K * N;    dst = T2 + (size_t)slice * N * K;
  }
  __shared__ float tile[64][33];
  int nn = threadIdx.x & 31, kk = threadIdx.x >> 5;       // read: 32n x 8k
#pragma unroll
  for (int i = 0; i < 8; i++) {
    int k = kk + 8 * i, n = n0 + nn;
    tile[k][nn] = (n < N) ? src[(size_t)(k0 + k) * N + n] : 0.0f;
  }
  __syncthreads();
  int kk2 = threadIdx.x & 63, nn2 = threadIdx.x >> 6;     // write: 64k x 4n
#pragma unroll
  for (int i = 0; i < 8; i++) {
    int n = nn2 + 4 * i;
    if (n0 + n < N)
      dst[(size_t)(n0 + n) * K + k0 + kk2] = (bf16)tile[kk2][n];
  }
}

// ---------------- bf16 MFMA GEMM, global_load_lds staging -------------------
// MODE 0: f32 out  MODE 1: +bias,gelu,bf16 out  MODE 3: bf16 out + f32 dt tail
template<int BM, int BN, int FI, int FJ, int MODE>
__global__ __launch_bounds__(256) void gemm_tile(
    const bf16* __restrict__ A, const bf16* __restrict__ BT,
    float* __restrict__ Cf, bf16* __restrict__ Cb,
    int M, int N, int K, int lda, int ldb,
    long aOffz, long bOffz, long cOffz, int flipz,
    const float* __restrict__ bias)
{
  constexpr int TG = (BM + BN) * 4;
  constexpr int NI = TG / 256;

  int z = blockIdx.z;
  A  += (size_t)z * aOffz;
  BT += (size_t)z * bOffz;
  long coff = (size_t)z * cOffz;
  int doflip = (flipz && z == 1);

  __shared__ __align__(16) bf16 Tile[(BM + BN) * 32];
  bf16* As = Tile;
  bf16* Bs = Tile + BM * 32;

  int m0 = blockIdx.x * BM, n0 = blockIdx.y * BN;
  int t = threadIdx.x;
  int lane = t & 63, w = t >> 6;
  int wr = w >> 1, wc = w & 1;
  int lr = lane & 15, lq = lane >> 4;

  const bf16* gsrc[NI];
#pragma unroll
  for (int i = 0; i < NI; i++) {
    int g = w * (TG / 4) + i * 64 + lane;
    if (g < BM * 4) {
      int row = g >> 2, kp = g & 3;
      int gr = m0 + row;
      if (doflip) gr ^= (L_SEQ - 1);
      gsrc[i] = A + (size_t)gr * lda + kp * 8;
    } else {
      int g2 = g - BM * 4;
      int row = g2 >> 2, kp = g2 & 3;
      int gn = n0 + row; if (gn >= N) gn = N - 1;
      gsrc[i] = BT + (size_t)gn * ldb + kp * 8;
    }
  }

  f32x4 zf = {0.0f, 0.0f, 0.0f, 0.0f};
  f32x4 acc[FI][FJ];
#pragma unroll
  for (int i = 0; i < FI; i++)
#pragma unroll
    for (int j = 0; j < FJ; j++) acc[i][j] = zf;

  for (int k0 = 0; k0 < K; k0 += 32) {
#pragma unroll
    for (int i = 0; i < NI; i++) {
      int chunk = w * (TG / 4) + i * 64;
      __builtin_amdgcn_global_load_lds(
          (const __attribute__((address_space(1))) void*)(gsrc[i] + k0),
          (__attribute__((address_space(3))) void*)&Tile[chunk * 8],
          16, 0, 0);
    }
    __syncthreads();

    bf16x8 af[FI], bfv[FJ];
#pragma unroll
    for (int i = 0; i < FI; i++)
      af[i] = *(const bf16x8*)&As[(wr * 64 + i * 16 + lr) * 32 + lq * 8];
#pragma unroll
    for (int j = 0; j < FJ; j++)
      bfv[j] = *(const bf16x8*)&Bs[(wc * (BN / 2) + j * 16 + lr) * 32 + lq * 8];
#pragma unroll
    for (int i = 0; i < FI; i++)
#pragma unroll
      for (int j = 0; j < FJ; j++)
        acc[i][j] = __builtin_amdgcn_mfma_f32_16x16x32_bf16(af[i], bfv[j], acc[i][j], 0, 0, 0);
    __syncthreads();
  }

#pragma unroll
  for (int i = 0; i < FI; i++) {
    int growb = m0 + wr * 64 + i * 16 + lq * 4;
#pragma unroll
    for (int j = 0; j < FJ; j++) {
      int gcol = n0 + wc * (BN / 2) + j * 16 + lr;
      if (gcol >= N) continue;
#pragma unroll
      for (int rr = 0; rr < 4; rr++) {
        int grow = growb + rr;
        float v = acc[i][j][rr];
        if (MODE == 1) {
          v += bias[gcol];
          v = 0.5f * v * (1.0f + erff(v * 0.70710678118f));
          Cb[coff + (size_t)grow * N + gcol] = (bf16)v;
        } else if (MODE == 3) {
          Cb[coff + (size_t)grow * N + gcol] = (bf16)v;
          if (gcol >= DINNER + CONVDIM)
            Cf[(size_t)z * ROWS * 16 + (size_t)grow * 16 + (gcol - (DINNER + CONVDIM))] = v;
        } else {
          Cf[coff + (size_t)grow * N + gcol] = v;
        }
      }
    }
  }
}

// ------ conv+silu for the 32 B/C channels only (compact f32 out) + dt/dA ----
__global__ __launch_bounds__(64) void convdt_bc(
    const bf16* __restrict__ ZX, const float* __restrict__ DTRAW,
    float* __restrict__ BCf, float* __restrict__ DT, float* __restrict__ DA,
    const float* __restrict__ conv_w, const float* __restrict__ conv_b,
    const float* __restrict__ dt_bias, const float* __restrict__ A_log)
{
  int r = blockIdx.x, dir = blockIdx.y;
  int l = r & (L_SEQ - 1);
  int t = threadIdx.x;
  if (t < 32) {
    int ch = DINNER + t;             // conv channel 1024+t (B/C block)
    const float* cw = conv_w + ((size_t)dir * CONVDIM + ch) * 4;
    float acc = conv_b[(size_t)dir * CONVDIM + ch];
    const bf16* zc = ZX + (size_t)dir * ROWS * DINPROJ + DINNER + ch;
#pragma unroll
    for (int k = 0; k < 4; k++) {
      int ls = l + k - 3;
      if (ls >= 0) acc += (float)zc[(size_t)(r + k - 3) * DINPROJ] * cw[k];
    }
    BCf[((size_t)dir * ROWS + r) * 32 + t] = silu_f(acc);
  } else if (t < 48) {
    int h = t - 32;
    float raw = DTRAW[((size_t)dir * ROWS + r) * 16 + h] + dt_bias[dir * NHEADS + h];
    float dt = (raw > 20.0f) ? raw : log1pf(expf(raw));
    float A = -expf(A_log[dir * NHEADS + h]);
    size_t idx = ((size_t)dir * ROWS + r) * NHEADS + h;
    DT[idx] = dt;
    DA[idx] = expf(dt * A);
  }
}

// ---- chunked SSM scan pass 1: inline x-conv (sliding window) + local scan,
//      writes y + D*x (bf16). One wave per (dir,b,head,chunk). ----
__global__ __launch_bounds__(64) void scan1_kernel(
    const bf16* __restrict__ ZX, const float* __restrict__ BCf,
    const float* __restrict__ DT, const float* __restrict__ DA,
    bf16* __restrict__ YSSM, float* __restrict__ HEND,
    float* __restrict__ APROD,
    const float* __restrict__ conv_w, const float* __restrict__ conv_b,
    const float* __restrict__ Dparam)
{
  int bid = blockIdx.x;
  int g = bid >> 4, c = bid & 15;
  int dir = g >> 5, rem = g & 31;
  int b = rem >> 4, h = rem & 15;
  int lane = threadIdx.x;
  size_t rowbase = (size_t)dir * ROWS + b * L_SEQ + c * CHUNK;

  float dtv = DT[(rowbase + lane) * NHEADS + h];
  float dav = DA[(rowbase + lane) * NHEADS + h];

  float ap = dav;
#pragma unroll
  for (int off = 1; off < 64; off <<= 1) {
    float o = __shfl_up(ap, off, 64);
    if (lane >= off) ap *= o;
  }
  APROD[((size_t)g * NCHUNK + c) * 64 + lane] = ap;

  // stage conv'd B|C (32 f32/row) into LDS
  __shared__ float BCs[CHUNK][36];
#pragma unroll
  for (int i = 0; i < 8; i++) {
    int l = i * 8 + (lane >> 3), f = lane & 7;
    float4 v = *(const float4*)&BCf[(rowbase + l) * 32 + f * 4];
    *(float4*)&BCs[l][f * 4] = v;
  }
  __syncthreads();

  // x-conv setup: lane owns channel ch = h*64+lane; sliding 4-tap window
  int ch = h * HEADDIM + lane;
  f32x4 cwv = *(const f32x4*)&conv_w[((size_t)dir * CONVDIM + ch) * 4];
  float cbv = conv_b[(size_t)dir * CONVDIM + ch];
  const bf16* xcol = ZX + rowbase * DINPROJ + DINNER + ch;  // stride DINPROJ
  int lg0 = c * CHUNK;   // global seq pos of chunk start
  float xm3 = (lg0 >= 3) ? (float)xcol[-3 * DINPROJ] : 0.0f;
  float xm2 = (lg0 >= 2) ? (float)xcol[-2 * DINPROJ] : 0.0f;
  float xm1 = (lg0 >= 1) ? (float)xcol[-1 * DINPROJ] : 0.0f;

  float Dv = Dparam[dir * NHEADS + h];

  float hs[16];
#pragma unroll
  for (int n = 0; n < 16; n++) hs[n] = 0.0f;

  bf16* yp = YSSM + rowbase * DINNER + ch;

  for (int l = 0; l < CHUNK; l++) {
    float dt = __shfl(dtv, l, 64);
    float da = __shfl(dav, l, 64);
    float xcur = (float)xcol[(size_t)l * DINPROJ];
    float conv = cbv + cwv[0]*xm3 + cwv[1]*xm2 + cwv[2]*xm1 + cwv[3]*xcur;
    xm3 = xm2; xm2 = xm1; xm1 = xcur;
    float xv = silu_f(conv);
    float4 bq[4], cq[4];
#pragma unroll
    for (int q = 0; q < 4; q++) {
      bq[q] = *(const float4*)&BCs[l][q * 4];
      cq[q] = *(const float4*)&BCs[l][16 + q * 4];
    }
    const float* Bv = (const float*)bq;
    const float* Cv = (const float*)cq;
    float dtx = dt * xv;
    float acc = 0.0f;
#pragma unroll
    for (int n = 0; n < 16; n++) {
      hs[n] = hs[n] * da + dtx * Bv[n];
      acc += hs[n] * Cv[n];
    }
    yp[(size_t)l * DINNER] = (bf16)(acc + Dv * xv);
  }

  float* he = HEND + ((size_t)g * NCHUNK + c) * 16 * 64;
#pragma unroll
  for (int n = 0; n < 16; n++) he[n * 64 + lane] = hs[n];
}

// ---------------- chunked SSM scan, pass 2: cross-chunk correction --------
__global__ __launch_bounds__(64) void scan2_kernel(
    const float* __restrict__ BCf, bf16* __restrict__ YSSM,
    const float* __restrict__ HEND, const float* __restrict__ APROD)
{
  int bid = blockIdx.x;
  int g = bid >> 4, c = bid & 15;
  if (c == 0) return;
  int dir = g >> 5, rem = g & 31;
  int b = rem >> 4, h = rem & 15;
  int lane = threadIdx.x;

  float hstart[16];
#pragma unroll
  for (int n = 0; n < 16; n++) hstart[n] = 0.0f;
  float w = 1.0f;
  for (int j = c - 1; j >= 0; j--) {
    const float* he = HEND + ((size_t)g * NCHUNK + j) * 16 * 64;
#pragma unroll
    for (int n = 0; n < 16; n++) hstart[n] += w * he[n * 64 + lane];
    w *= APROD[((size_t)g * NCHUNK + j) * 64 + 63];
  }

  size_t rowbase = (size_t)dir * ROWS + b * L_SEQ + c * CHUNK;
  bf16* yp = YSSM + rowbase * DINNER + h * HEADDIM + lane;
  float apv = APROD[((size_t)g * NCHUNK + c) * 64 + lane];

  __shared__ float Cs[CHUNK][20];
#pragma unroll
  for (int i = 0; i < 4; i++) {
    int l = i * 16 + (lane >> 2), f = lane & 3;
    float4 v = *(const float4*)&BCf[(rowbase + l) * 32 + 16 + f * 4];
    *(float4*)&Cs[l][f * 4] = v;
  }
  __syncthreads();

  for (int l = 0; l < CHUNK; l++) {
    float a = __shfl(apv, l, 64);
    float4 cq[4];
#pragma unroll
    for (int q = 0; q < 4; q++) cq[q] = *(const float4*)&Cs[l][q * 4];
    const float* Cv = (const float*)cq;
    float acc = 0.0f;
#pragma unroll
    for (int n = 0; n < 16; n++) acc += Cv[n] * hstart[n];
    float y = (float)yp[(size_t)l * DINNER];
    yp[(size_t)l * DINNER] = (bf16)(y + a * acc);
  }
}

// ------- gate (y already has D*x): y*silu(z) + RMS(1024), bf16 out -------
__global__ __launch_bounds__(256) void gatenorm_kernel(
    const bf16* __restrict__ YSSM, const bf16* __restrict__ ZX,
    const float* __restrict__ mnorm_w, bf16* __restrict__ YB)
{
  int r = blockIdx.x, dir = blockIdx.y, t = threadIdx.x;
  const bf16* y = YSSM + ((size_t)dir * ROWS + r) * DINNER;
  const bf16* z  = ZX  + ((size_t)dir * ROWS + r) * DINPROJ;
  int c = t * 4;
  bf16x4 yv4 = *(const bf16x4*)&y[c];
  bf16x4 zv4 = *(const bf16x4*)&z[c];
  float val[4];
#pragma unroll
  for (int q = 0; q < 4; q++)
    val[q] = (float)yv4[q] * silu_f((float)zv4[q]);
  float ss = val[0]*val[0] + val[1]*val[1] + val[2]*val[2] + val[3]*val[3];
  ss = wave_sum(ss);
  __shared__ float red[4];
  if ((t & 63) == 0) red[t >> 6] = ss;
  __syncthreads();
  float total = red[0] + red[1] + red[2] + red[3];
  float rs = 1.0f / sqrtf(total * (1.0f / DINNER) + 1e-5f);
  float4 wv = *(const float4*)&mnorm_w[dir * DINNER + c];
  bf16x4 o;
  o[0] = (bf16)(val[0] * rs * wv.x);
  o[1] = (bf16)(val[1] * rs * wv.y);
  o[2] = (bf16)(val[2] * rs * wv.z);
  o[3] = (bf16)(val[3] * rs * wv.w);
  *(bf16x4*)&YB[((size_t)dir * ROWS + r) * DINNER + c] = o;
}

// ------ combine (x += 0.5*(f+flip(b))*mask) + FFN RMS, bf16 out ------
__global__ __launch_bounds__(128) void combine_rms(
    const float* __restrict__ Xsrc, float* __restrict__ X,
    const float* __restrict__ P, const float* __restrict__ mask,
    const float* __restrict__ w, bf16* __restrict__ outb)
{
  int r = blockIdx.x, t = threadIdx.x;
  int b = r >> 10, l = r & 1023;
  int c = t * 4;
  float m = 0.5f * mask[r];
  float4 f = *(const float4*)&P[(size_t)r * DMODEL + c];
  size_t br = (size_t)ROWS * DMODEL + ((size_t)(b * L_SEQ + (L_SEQ - 1 - l))) * DMODEL + c;
  float4 bw = *(const float4*)&P[br];
  float4 x = *(const float4*)&Xsrc[(size_t)r * DMODEL + c];
  x.x += m * (f.x + bw.x);
  x.y += m * (f.y + bw.y);
  x.z += m * (f.z + bw.z);
  x.w += m * (f.w + bw.w);
  *(float4*)&X[(size_t)r * DMODEL + c] = x;
  float ss = x.x*x.x + x.y*x.y + x.z*x.z + x.w*x.w;
  ss = wave_sum(ss);
  __shared__ float red[2];
  if ((t & 63) == 0) red[t >> 6] = ss;
  __syncthreads();
  float rs = 1.0f / sqrtf((red[0] + red[1]) * (1.0f / DMODEL) + 1e-6f);
  float4 wv = *(const float4*)&w[c];
  bf16x4 o;
  o[0] = (bf16)(x.x * rs * wv.x);
  o[1] = (bf16)(x.y * rs * wv.y);
  o[2] = (bf16)(x.z * rs * wv.z);
  o[3] = (bf16)(x.w * rs * wv.w);
  *(bf16x4*)&outb[(size_t)r * DMODEL + c] = o;
}

// ------ FFN2 splitK reduce + bias + resid, then RMS (next-layer or final) ---
__global__ __launch_bounds__(128) void reduce_rms(
    float* __restrict__ X, const float* __restrict__ P,
    const float* __restrict__ bias, const float* __restrict__ w,
    const float* __restrict__ pe, const float* __restrict__ mask,
    bf16* __restrict__ outb, float* __restrict__ outf)
{
  int r = blockIdx.x, t = threadIdx.x;
  int c = t * 4;
  float4 a  = *(const float4*)&P[(size_t)r * DMODEL + c];
  float4 b2 = *(const float4*)&P[(size_t)ROWS * DMODEL + (size_t)r * DMODEL + c];
  float4 bi = *(const float4*)&bias[c];
  float4 x  = *(float4*)&X[(size_t)r * DMODEL + c];
  x.x += a.x + b2.x + bi.x;
  x.y += a.y + b2.y + bi.y;
  x.z += a.z + b2.z + bi.z;
  x.w += a.w + b2.w + bi.w;
  *(float4*)&X[(size_t)r * DMODEL + c] = x;
  float ss = x.x*x.x + x.y*x.y + x.z*x.z + x.w*x.w;
  ss = wave_sum(ss);
  __shared__ float red[2];
  if ((t & 63) == 0) red[t >> 6] = ss;
  __syncthreads();
  float rs = 1.0f / sqrtf((red[0] + red[1]) * (1.0f / DMODEL) + 1e-6f);
  float4 wv = *(const float4*)&w[c];
  float4 o;
  o.x = x.x*rs*wv.x; o.y = x.y*rs*wv.y; o.z = x.z*rs*wv.z; o.w = x.w*rs*wv.w;
  if (pe) {
    float4 p = *(const float4*)&pe[(size_t)r * DMODEL + c];
    float m = mask[r];
    o.x = (o.x + p.x)*m; o.y = (o.y + p.y)*m; o.z = (o.z + p.z)*m; o.w = (o.w + p.w)*m;
  }
  if (outb) {
    bf16x4 ob = {(bf16)o.x, (bf16)o.y, (bf16)o.z, (bf16)o.w};
    *(bf16x4*)&outb[(size_t)r * DMODEL + c] = ob;
  } else {
    *(float4*)&outf[(size_t)r * DMODEL + c] = o;
  }
}

// ---------------- host ----------------
extern "C" void kernel_launch(void* const* d_in, const int* in_sizes, int n_in,
                              void* d_out, int out_size, void* d_ws, size_t ws_size,
                              hipStream_t stream)
{
  const float* in_x    = (const float*)d_in[0];
  const float* in_pe   = (const float*)d_in[1];
  const float* in_mask = (const float*)d_in[2];
  const float* W_in    = (const float*)d_in[3];
  const float* conv_w  = (const float*)d_in[4];
  const float* conv_b  = (const float*)d_in[5];
  const float* A_log   = (const float*)d_in[6];
  const float* Dparam  = (const float*)d_in[7];
  const float* dt_bias = (const float*)d_in[8];
  const float* mnorm_w = (const float*)d_in[9];
  const float* W_out   = (const float*)d_in[10];
  const float* nssm_w  = (const float*)d_in[11];
  const float* ffn_w1  = (const float*)d_in[12];
  const float* ffn_b1  = (const float*)d_in[13];
  const float* ffn_w2  = (const float*)d_in[14];
  const float* ffn_b2  = (const float*)d_in[15];
  const float* nffn_w  = (const float*)d_in[16];
  const float* final_w = (const float*)d_in[17];

  if (ws_size < 126287872) return;

  // offsets (running sums verified):
  char* ws = (char*)d_ws;
  float* XBUF  = (float*)(ws + 0);            //  4,194,304 -> 4,194,304
  bf16*  SBUF  = (bf16*) (ws + 4194304);      //  2,097,152 -> 6,291,456
  bf16*  ZXb   = (bf16*) (ws + 6291456);      // 17,170,432 -> 23,461,888
  float* DTRAW = (float*)(ws + 23461888);     //    262,144 -> 23,724,032
  float* BCf   = (float*)(ws + 23724032);     //    524,288 -> 24,248,320
  float* DTb   = (float*)(ws + 24248320);     //    262,144 -> 24,510,464
  float* DAb   = (float*)(ws + 24510464);     //    262,144 -> 24,772,608
  bf16*  YSSMb = (bf16*) (ws + 24772608);     //  8,388,608 -> 33,161,216
  bf16*  YB    = (bf16*) (ws + 33161216);     //  8,388,608 -> 41,549,824
  float* DOUT2 = (float*)(ws + 41549824);     //  8,388,608 -> 49,938,432
  bf16*  MID   = (bf16*) (ws + 49938432);     //  8,388,608 -> 58,327,040
  float* HEND  = (float*)(ws + 58327040);     //  4,194,304 -> 62,521,344
  float* APROD = (float*)(ws + 62521344);     //    262,144 -> 62,783,488
  bf16*  WTINa = (bf16*) (ws + 62783488);     // 25,755,648 -> 88,539,136
  bf16*  WTOUTa= (bf16*) (ws + 88539136);     // 12,582,912 -> 101,122,048
  bf16*  WT1a  = (bf16*) (ws + 101122048);    // 12,582,912 -> 113,704,960
  bf16*  WT2a  = (bf16*) (ws + 113704960);    // 12,582,912 -> 126,287,872

  transpose_all<<<15552, 256, 0, stream>>>(W_in, W_out, ffn_w1, ffn_w2,
                                           WTINa, WTOUTa, WT1a, WT2a);
  rms_kernel<<<ROWS, 128, 0, stream>>>(in_x, nssm_w, in_pe, in_mask, SBUF);

  for (int layer = 0; layer < 6; layer++) {
    const bf16* WTIN  = WTINa  + (size_t)layer * 2 * DMODEL * DINPROJ;
    const bf16* WTOUT = WTOUTa + (size_t)layer * 2 * DINNER * DMODEL;
    const bf16* WT1   = WT1a   + (size_t)layer * DMODEL * FFN_DIM;
    const bf16* WT2   = WT2a   + (size_t)layer * FFN_DIM * DMODEL;
    const float* cw_l = conv_w + (size_t)layer * 2 * CONVDIM * 4;
    const float* cb_l = conv_b + (size_t)layer * 2 * CONVDIM;

    gemm_tile<128, 128, 4, 4, 3><<<dim3(16, 17, 2), 256, 0, stream>>>(
        SBUF, WTIN, DTRAW, ZXb, ROWS, DINPROJ, DMODEL, DMODEL, DMODEL,
        0L, (long)DINPROJ * DMODEL, (long)ROWS * DINPROJ, 1, nullptr);
    convdt_bc<<<dim3(ROWS, 2), 64, 0, stream>>>(
        ZXb, DTRAW, BCf, DTb, DAb, cw_l, cb_l,
        dt_bias + layer * 2 * NHEADS, A_log + layer * 2 * NHEADS);
    scan1_kernel<<<1024, 64, 0, stream>>>(
        ZXb, BCf, DTb, DAb, YSSMb, HEND, APROD, cw_l, cb_l,
        Dparam + layer * 2 * NHEADS);
    scan2_kernel<<<1024, 64, 0, stream>>>(BCf, YSSMb, HEND, APROD);
    gatenorm_kernel<<<dim3(ROWS, 2), 256, 0, stream>>>(
        YSSMb, ZXb, mnorm_w + layer * 2 * DINNER, YB);
    gemm_tile<128, 64, 4, 2, 0><<<dim3(16, 8, 2), 256, 0, stream>>>(
        YB, WTOUT, DOUT2, nullptr, ROWS, DMODEL, DINNER, DINNER, DINNER,
        (long)ROWS * DINNER, (long)DMODEL * DINNER, (long)ROWS * DMODEL, 0, nullptr);
    combine_rms<<<ROWS, 128, 0, stream>>>(
        layer == 0 ? in_x : XBUF, XBUF, DOUT2, in_mask, nffn_w + layer * DMODEL, SBUF);

    // FFN (FFN1 now 128x64 tiles -> 512 blocks for latency overlap)
    gemm_tile<128, 64, 4, 2, 1><<<dim3(16, 32, 1), 256, 0, stream>>>(
        SBUF, WT1, nullptr, MID, ROWS, FFN_DIM, DMODEL, DMODEL, DMODEL,
        0L, 0L, 0L, 0, ffn_b1 + layer * FFN_DIM);
    gemm_tile<128, 64, 4, 2, 0><<<dim3(16, 8, 2), 256, 0, stream>>>(
        MID, WT2, DOUT2, nullptr, ROWS, DMODEL, 1024, FFN_DIM, FFN_DIM,
        1024L, 1024L, (long)ROWS * DMODEL, 0, nullptr);
    if (layer < 5) {
      reduce_rms<<<ROWS, 128, 0, stream>>>(
          XBUF, DOUT2, ffn_b2 + layer * DMODEL, nssm_w + (layer + 1) * DMODEL,
          in_pe, in_mask, SBUF, nullptr);
    } else {
      reduce_rms<<<ROWS, 128, 0, stream>>>(
          XBUF, DOUT2, ffn_b2 + layer * DMODEL, final_w,
          nullptr, nullptr, nullptr, (float*)d_out);
    }
  }
}